// Round 1
// baseline (2609.281 us; speedup 1.0000x reference)
//
#include <hip/hip_runtime.h>
#include <math.h>

#define NPIX 4096
#define NROWS 16384      // B*N
#define KN 20
#define MTOT 327680.0    // B*N*K

// ---------------- conv1: 5x5, 1->64, pad 2, tanh ----------------
__global__ __launch_bounds__(256) void conv1_k(const float* __restrict__ x,
    const float* __restrict__ w, const float* __restrict__ bias,
    float* __restrict__ out) {
  int b = blockIdx.x, co = blockIdx.y;
  __shared__ float tile[68*68];
  __shared__ float wt[25];
  const float* src = x + b*NPIX;
  for (int i = threadIdx.x; i < 68*68; i += 256) {
    int r = i/68 - 2, c = i%68 - 2;
    tile[i] = (r>=0 && r<64 && c>=0 && c<64) ? src[r*64+c] : 0.f;
  }
  if (threadIdx.x < 25) wt[threadIdx.x] = w[co*25 + threadIdx.x];
  __syncthreads();
  float bv = bias[co];
  for (int p = threadIdx.x; p < NPIX; p += 256) {
    int r = p >> 6, c = p & 63;
    float acc = bv;
#pragma unroll
    for (int di=0; di<5; di++)
#pragma unroll
      for (int dj=0; dj<5; dj++)
        acc = fmaf(tile[(r+di)*68 + c+dj], wt[di*5+dj], acc);
    out[(b*64+co)*NPIX + p] = tanhf(acc);
  }
}

// ---------------- generic 3x3 conv, pad 1, 16x16 spatial tile ----------------
template<int CIN, int COG, bool TANH>
__global__ __launch_bounds__(256) void conv3x3_k(const float* __restrict__ in,
    const float* __restrict__ w, const float* __restrict__ bias,
    float* __restrict__ out, int cout_total) {
  int b = blockIdx.x, tile = blockIdx.y, cg = blockIdx.z;
  int th = (tile >> 2) << 4, tw = (tile & 3) << 4;
  int ty = threadIdx.x >> 4, tx = threadIdx.x & 15;
  __shared__ float s_in[18*18];
  __shared__ float s_w[COG*9];
  float acc[COG];
#pragma unroll
  for (int o=0;o<COG;o++) acc[o] = bias[cg*COG+o];
  for (int ci = 0; ci < CIN; ci++) {
    const float* src = in + ((size_t)(b*CIN + ci) << 12);
    for (int i = threadIdx.x; i < 18*18; i += 256) {
      int r = th + i/18 - 1, c = tw + i%18 - 1;
      s_in[i] = (r>=0 && r<64 && c>=0 && c<64) ? src[(r<<6)+c] : 0.f;
    }
    for (int i = threadIdx.x; i < COG*9; i += 256) {
      int o = i/9, t = i - o*9;
      s_w[i] = w[((cg*COG+o)*CIN + ci)*9 + t];
    }
    __syncthreads();
    float v[9];
#pragma unroll
    for (int di=0;di<3;di++)
#pragma unroll
      for (int dj=0;dj<3;dj++)
        v[di*3+dj] = s_in[(ty+di)*18 + tx+dj];
#pragma unroll
    for (int o=0;o<COG;o++)
#pragma unroll
      for (int t=0;t<9;t++)
        acc[o] = fmaf(v[t], s_w[o*9+t], acc[o]);
    __syncthreads();
  }
#pragma unroll
  for (int o=0;o<COG;o++) {
    float r = TANH ? tanhf(acc[o]) : acc[o];
    out[((size_t)(b*cout_total + cg*COG + o) << 12) + ((th+ty)<<6) + (tw+tx)] = r;
  }
}

// ---------------- KNN: per row, 21 smallest (dist, idx), drop rank 0 ----------------
// dist replicates the reference f32 op sequence exactly:
//   sq = f*f;  dist = (sq_n + sq_m) - 2*(f_n*f_m)
// key = (sign-flipped f32 dist) << 32 | m   -> lexicographic (dist, idx), matching
// stable argsort tie semantics.
__global__ __launch_bounds__(256) void knn_k(const float* __restrict__ f,
    float* __restrict__ dout) {
  int b = blockIdx.x >> 4, grp = blockIdx.x & 15;
  __shared__ float sf[NPIX];
  __shared__ float ssq[NPIX];
  const float* fb = f + b*NPIX;
  for (int i = threadIdx.x; i < NPIX; i += 256) {
    float v = fb[i];
    sf[i] = v;
    ssq[i] = __fmul_rn(v, v);
  }
  __syncthreads();
  int n = (grp << 8) + threadIdx.x;
  float fn = sf[n], sqn = ssq[n];
  unsigned long long key[21];
#pragma unroll
  for (int i=0;i<21;i++) key[i] = ~0ULL;
  for (int m = 0; m < NPIX; m++) {
    float pr = __fmul_rn(fn, sf[m]);
    float dist = __fsub_rn(__fadd_rn(sqn, ssq[m]), __fmul_rn(2.0f, pr));
    unsigned u = __float_as_uint(dist);
    u ^= (u >> 31) ? 0xFFFFFFFFu : 0x80000000u;
    unsigned long long kk = (((unsigned long long)u) << 32) | (unsigned)m;
    if (kk < key[20]) {
#pragma unroll
      for (int i=0;i<21;i++) {
        unsigned long long a = key[i];
        bool lt = kk < a;
        unsigned long long mn = lt ? kk : a;
        kk = lt ? a : kk;
        key[i] = mn;
      }
    }
  }
  float* dd = dout + (size_t)(b*NPIX + n)*KN;
#pragma unroll
  for (int i=1;i<=20;i++) {
    int m = (int)(key[i] & 0xFFFFFFFFu);
    dd[i-1] = __fsub_rn(sf[m], fn);   // knn - x1
  }
}

// ---------------- joint moments of (f, d) for BN1 (shared by all branches) ----------------
__global__ __launch_bounds__(256) void stats_k(const float* __restrict__ f,
    const float* __restrict__ dw, double* __restrict__ part) {
  int row = blockIdx.x*256 + threadIdx.x;
  float fv = f[row];
  const float* dd = dw + (size_t)row*KN;
  double sd = 0.0, sdd = 0.0;
#pragma unroll
  for (int k=0;k<KN;k++) { double d = (double)dd[k]; sd += d; sdd += d*d; }
  double q[5];
  q[0] = (double)fv;
  q[1] = (double)fv * (double)fv;
  q[2] = sd;
  q[3] = sdd;
  q[4] = (double)fv * sd;
  __shared__ double sred[4][5];
  int wid = threadIdx.x >> 6, lane = threadIdx.x & 63;
#pragma unroll
  for (int qi=0; qi<5; qi++) {
    double v = q[qi];
    for (int off=32; off>0; off>>=1) v += __shfl_down(v, off, 64);
    if (lane == 0) sred[wid][qi] = v;
  }
  __syncthreads();
  if (threadIdx.x == 0) {
#pragma unroll
    for (int qi=0; qi<5; qi++)
      part[blockIdx.x*5 + qi] = sred[0][qi]+sred[1][qi]+sred[2][qi]+sred[3][qi];
  }
}

// ---------------- fold BN1 into per-channel affine consts A,B,C per branch ----------------
__global__ void finalize1_k(const double* __restrict__ part,
    const float* __restrict__ ew1, const float* __restrict__ eb1,
    const float* __restrict__ eg1, const float* __restrict__ ebt1,
    float* __restrict__ consts1) {
  if (threadIdx.x || blockIdx.x) return;
  double S[5] = {0,0,0,0,0};
  for (int blk=0; blk<64; blk++)
    for (int q=0;q<5;q++) S[q] += part[blk*5+q];
  double Ef = S[0]/16384.0, Eff = S[1]/16384.0;
  double Ed = S[2]/MTOT, Edd = S[3]/MTOT, Efd = S[4]/MTOT;
  double Vf = Eff - Ef*Ef, Vd = Edd - Ed*Ed, Cfd = Efd - Ef*Ed;
  for (int br=0; br<3; br++)
    for (int c=0; c<16; c++) {
      int idx = br*16 + c;
      double w0 = (double)ew1[idx*2+0], w1 = (double)ew1[idx*2+1];
      double b1 = (double)eb1[idx];
      double m1 = w0*Ef + w1*Ed + b1;
      double v1 = w0*w0*Vf + 2.0*w0*w1*Cfd + w1*w1*Vd;
      double r1 = 1.0 / sqrt(v1 + 1e-5);
      double g = (double)eg1[idx];
      consts1[idx*3+0] = (float)(g*r1*w0);
      consts1[idx*3+1] = (float)(g*r1*w1);
      consts1[idx*3+2] = (float)(g*r1*(b1 - m1) + (double)ebt1[idx]);
    }
}

// ---------------- per-branch o_pre: max/min over k + BN2 moments ----------------
__global__ __launch_bounds__(256) void branch_k(const float* __restrict__ f,
    const float* __restrict__ dw, const float* __restrict__ consts1,
    const float* __restrict__ ew2, const float* __restrict__ eb2,
    float* __restrict__ maxo, float* __restrict__ mino,
    double* __restrict__ part2) {
  int br = blockIdx.y;
  __shared__ float sA[16], sB[16], sC[16], sW[16];
  if (threadIdx.x < 16) {
    int idx = br*16 + threadIdx.x;
    sA[threadIdx.x] = consts1[idx*3+0];
    sB[threadIdx.x] = consts1[idx*3+1];
    sC[threadIdx.x] = consts1[idx*3+2];
    sW[threadIdx.x] = ew2[idx];
  }
  __syncthreads();
  int row = blockIdx.x*256 + threadIdx.x;
  float fv = f[row];
  const float* dd = dw + (size_t)row*KN;
  float b2 = eb2[br];
  float P[16];
#pragma unroll
  for (int c=0;c<16;c++) P[c] = fmaf(sA[c], fv, sC[c]);
  float mx = -INFINITY, mn = INFINITY;
  double s = 0.0, s2 = 0.0;
  for (int k=0;k<KN;k++) {
    float d = dd[k];
    float t = b2;
#pragma unroll
    for (int c=0;c<16;c++)
      t = fmaf(sW[c], fmaxf(fmaf(sB[c], d, P[c]), 0.f), t);
    mx = fmaxf(mx, t);
    mn = fminf(mn, t);
    double td = (double)t;
    s += td; s2 += td*td;
  }
  maxo[br*NROWS + row] = mx;
  mino[br*NROWS + row] = mn;
  __shared__ double sred[4][2];
  int wid = threadIdx.x >> 6, lane = threadIdx.x & 63;
  double v0 = s, v1 = s2;
  for (int off=32; off>0; off>>=1) {
    v0 += __shfl_down(v0, off, 64);
    v1 += __shfl_down(v1, off, 64);
  }
  if (lane == 0) { sred[wid][0] = v0; sred[wid][1] = v1; }
  __syncthreads();
  if (threadIdx.x == 0) {
    part2[(br*64 + blockIdx.x)*2 + 0] = sred[0][0]+sred[1][0]+sred[2][0]+sred[3][0];
    part2[(br*64 + blockIdx.x)*2 + 1] = sred[0][1]+sred[1][1]+sred[2][1]+sred[3][1];
  }
}

// ---------------- BN2 constants per branch ----------------
__global__ void finalize2_k(const double* __restrict__ part2,
    const float* __restrict__ eg2, const float* __restrict__ ebt2,
    float* __restrict__ consts2) {
  if (threadIdx.x || blockIdx.x) return;
  for (int br=0; br<3; br++) {
    double s=0, s2=0;
    for (int blk=0; blk<64; blk++) {
      s  += part2[(br*64+blk)*2+0];
      s2 += part2[(br*64+blk)*2+1];
    }
    double mean = s / MTOT;
    double var = s2 / MTOT - mean*mean;
    double r2 = 1.0 / sqrt(var + 1e-5);
    double sc = (double)eg2[br] * r2;
    consts2[br*2+0] = (float)sc;
    consts2[br*2+1] = (float)((double)ebt2[br] - sc*mean);
  }
}

// ---------------- pixel shuffle + sigmoid ----------------
// out[b,0,2h+i,2w+j]: ch = i*2+j; ch0 = conv4 output, ch1..3 = branches.
// max over k of relu(BN2(x)) = relu(BN2(max or min of x, by sign of scale)).
__global__ __launch_bounds__(256) void out_k(const float* __restrict__ f,
    const float* __restrict__ maxo, const float* __restrict__ mino,
    const float* __restrict__ consts2, float* __restrict__ out) {
  int tid = blockIdx.x*256 + threadIdx.x;   // 65536
  int b = tid >> 14;
  int y = (tid >> 7) & 127, xx = tid & 127;
  int n = ((y>>1)<<6) + (xx>>1);
  int ch = ((y&1)<<1) + (xx&1);
  float v;
  if (ch == 0) {
    v = f[b*NPIX + n];
  } else {
    int br = ch - 1;
    float sc = consts2[br*2+0], sh = consts2[br*2+1];
    float base = (sc >= 0.f) ? maxo[br*NROWS + b*NPIX + n]
                             : mino[br*NROWS + b*NPIX + n];
    v = fmaxf(fmaf(sc, base, sh), 0.f);
  }
  out[tid] = 1.f / (1.f + expf(-v));
}

extern "C" void kernel_launch(void* const* d_in, const int* in_sizes, int n_in,
                              void* d_out, int out_size, void* d_ws, size_t ws_size,
                              hipStream_t stream) {
  (void)in_sizes; (void)n_in; (void)out_size; (void)ws_size;
  const float* x    = (const float*)d_in[0];
  const float* c1w  = (const float*)d_in[1];
  const float* c1b  = (const float*)d_in[2];
  const float* c2w  = (const float*)d_in[3];
  const float* c2b  = (const float*)d_in[4];
  const float* c3w  = (const float*)d_in[5];
  const float* c3b  = (const float*)d_in[6];
  const float* c4w  = (const float*)d_in[7];
  const float* c4b  = (const float*)d_in[8];
  const float* ew1  = (const float*)d_in[9];
  const float* eb1  = (const float*)d_in[10];
  const float* eg1  = (const float*)d_in[11];
  const float* ebt1 = (const float*)d_in[12];
  const float* ew2  = (const float*)d_in[13];
  const float* eb2  = (const float*)d_in[14];
  const float* eg2  = (const float*)d_in[15];
  const float* ebt2 = (const float*)d_in[16];
  float* out = (float*)d_out;

  float* c1      = (float*)d_ws;             // 1048576 floats
  float* c2      = c1 + 1048576;             // 524288
  float* c3      = c2 + 524288;              // 262144
  float* fbuf    = c3 + 262144;              // 16384
  float* dw      = fbuf + 16384;             // 327680
  double* part1  = (double*)(dw + 327680);   // 320  (8B aligned by construction)
  float* consts1 = (float*)(part1 + 320);    // 144
  double* part2  = (double*)(consts1 + 144); // 384
  float* maxo    = (float*)(part2 + 384);    // 49152
  float* mino    = maxo + 49152;             // 49152
  float* consts2 = mino + 49152;             // 6

  conv1_k<<<dim3(4,64), 256, 0, stream>>>(x, c1w, c1b, c1);
  conv3x3_k<64,16,true ><<<dim3(4,16,2), 256, 0, stream>>>(c1, c2w, c2b, c2, 32);
  conv3x3_k<32,16,true ><<<dim3(4,16,1), 256, 0, stream>>>(c2, c3w, c3b, c3, 16);
  conv3x3_k<16, 1,false><<<dim3(4,16,1), 256, 0, stream>>>(c3, c4w, c4b, fbuf, 1);
  knn_k<<<64, 256, 0, stream>>>(fbuf, dw);
  stats_k<<<64, 256, 0, stream>>>(fbuf, dw, part1);
  finalize1_k<<<1, 64, 0, stream>>>(part1, ew1, eb1, eg1, ebt1, consts1);
  branch_k<<<dim3(64,3), 256, 0, stream>>>(fbuf, dw, consts1, ew2, eb2, maxo, mino, part2);
  finalize2_k<<<1, 64, 0, stream>>>(part2, eg2, ebt2, consts2);
  out_k<<<256, 256, 0, stream>>>(fbuf, maxo, mino, consts2, out);
}

// Round 2
// 318.309 us; speedup vs baseline: 8.1973x; 8.1973x over previous
//
#include <hip/hip_runtime.h>
#include <math.h>

#define NPIX 4096
#define NROWS 16384      // B*N
#define KN 20
#define WIN 65           // sorted-order candidate window (32 each side + self)
#define MTOT 327680.0    // B*N*K

// ---------------- conv1: 5x5, 1->64, pad 2, tanh ----------------
__global__ __launch_bounds__(256) void conv1_k(const float* __restrict__ x,
    const float* __restrict__ w, const float* __restrict__ bias,
    float* __restrict__ out) {
  int b = blockIdx.x, co = blockIdx.y;
  __shared__ float tile[68*68];
  __shared__ float wt[25];
  const float* src = x + b*NPIX;
  for (int i = threadIdx.x; i < 68*68; i += 256) {
    int r = i/68 - 2, c = i%68 - 2;
    tile[i] = (r>=0 && r<64 && c>=0 && c<64) ? src[r*64+c] : 0.f;
  }
  if (threadIdx.x < 25) wt[threadIdx.x] = w[co*25 + threadIdx.x];
  __syncthreads();
  float bv = bias[co];
  for (int p = threadIdx.x; p < NPIX; p += 256) {
    int r = p >> 6, c = p & 63;
    float acc = bv;
#pragma unroll
    for (int di=0; di<5; di++)
#pragma unroll
      for (int dj=0; dj<5; dj++)
        acc = fmaf(tile[(r+di)*68 + c+dj], wt[di*5+dj], acc);
    out[(b*64+co)*NPIX + p] = tanhf(acc);
  }
}

// ---------------- generic 3x3 conv, pad 1, 16x16 spatial tile ----------------
template<int CIN, int COG, bool TANH>
__global__ __launch_bounds__(256) void conv3x3_k(const float* __restrict__ in,
    const float* __restrict__ w, const float* __restrict__ bias,
    float* __restrict__ out, int cout_total) {
  int b = blockIdx.x, tile = blockIdx.y, cg = blockIdx.z;
  int th = (tile >> 2) << 4, tw = (tile & 3) << 4;
  int ty = threadIdx.x >> 4, tx = threadIdx.x & 15;
  __shared__ float s_in[18*18];
  __shared__ float s_w[COG*9];
  float acc[COG];
#pragma unroll
  for (int o=0;o<COG;o++) acc[o] = bias[cg*COG+o];
  for (int ci = 0; ci < CIN; ci++) {
    const float* src = in + ((size_t)(b*CIN + ci) << 12);
    for (int i = threadIdx.x; i < 18*18; i += 256) {
      int r = th + i/18 - 1, c = tw + i%18 - 1;
      s_in[i] = (r>=0 && r<64 && c>=0 && c<64) ? src[(r<<6)+c] : 0.f;
    }
    for (int i = threadIdx.x; i < COG*9; i += 256) {
      int o = i/9, t = i - o*9;
      s_w[i] = w[((cg*COG+o)*CIN + ci)*9 + t];
    }
    __syncthreads();
    float v[9];
#pragma unroll
    for (int di=0;di<3;di++)
#pragma unroll
      for (int dj=0;dj<3;dj++)
        v[di*3+dj] = s_in[(ty+di)*18 + tx+dj];
#pragma unroll
    for (int o=0;o<COG;o++)
#pragma unroll
      for (int t=0;t<9;t++)
        acc[o] = fmaf(v[t], s_w[o*9+t], acc[o]);
    __syncthreads();
  }
#pragma unroll
  for (int o=0;o<COG;o++) {
    float r = TANH ? tanhf(acc[o]) : acc[o];
    out[((size_t)(b*cout_total + cg*COG + o) << 12) + ((th+ty)<<6) + (tw+tx)] = r;
  }
}

// ---------------- per-batch bitonic sort of (value, idx) ----------------
__global__ __launch_bounds__(1024) void sort_k(const float* __restrict__ f,
    float* __restrict__ sval, int* __restrict__ sidx, int* __restrict__ rank) {
  int b = blockIdx.x;
  __shared__ unsigned long long skey[NPIX];
  const float* fb = f + b*NPIX;
  for (int i = threadIdx.x; i < NPIX; i += 1024) {
    float v = fb[i];
    unsigned u = __float_as_uint(v);
    u ^= (u >> 31) ? 0xFFFFFFFFu : 0x80000000u;   // order-preserving flip
    skey[i] = (((unsigned long long)u) << 32) | (unsigned)i;
  }
  __syncthreads();
  for (int k = 2; k <= NPIX; k <<= 1) {
    for (int j = k >> 1; j > 0; j >>= 1) {
      for (int i = threadIdx.x; i < NPIX; i += 1024) {
        int p = i ^ j;
        if (p > i) {
          unsigned long long a = skey[i], c = skey[p];
          bool asc = ((i & k) == 0);
          if ((a > c) == asc) { skey[i] = c; skey[p] = a; }
        }
      }
      __syncthreads();
    }
  }
  for (int s = threadIdx.x; s < NPIX; s += 1024) {
    int idx = (int)(skey[s] & 0xFFFFFFFFu);
    sval[b*NPIX + s] = fb[idx];
    sidx[b*NPIX + s] = idx;
    rank[b*NPIX + idx] = s;
  }
}

// ---------------- KNN over sorted-order window ----------------
// Within the window, replicates the reference f32 op sequence exactly:
//   sq = f*f;  dist = (sq_n + sq_m) - 2*(f_n*f_m)
// key = (sign-flipped f32 dist) << 32 | m  -> lexicographic (dist, idx),
// matching stable-argsort tie semantics. Top-21 selected, rank 0 dropped.
__global__ __launch_bounds__(256) void knn2_k(const float* __restrict__ f,
    const float* __restrict__ sval, const int* __restrict__ sidx,
    const int* __restrict__ rank, float* __restrict__ dout) {
  int b = blockIdx.x >> 4, grp = blockIdx.x & 15;
  __shared__ float s_v[NPIX];     // sorted values
  __shared__ int   s_i[NPIX];     // original indices
  const float* svb = sval + b*NPIX;
  const int*   sib = sidx + b*NPIX;
  for (int i = threadIdx.x; i < NPIX; i += 256) {
    s_v[i] = svb[i];
    s_i[i] = sib[i];
  }
  __syncthreads();
  int n = (grp << 8) + threadIdx.x;
  int p = rank[b*NPIX + n];
  float fn = f[b*NPIX + n];
  float sqn = __fmul_rn(fn, fn);
  int start = p - 32;
  if (start < 0) start = 0;
  if (start > NPIX - WIN) start = NPIX - WIN;
  unsigned long long key[21];
#pragma unroll
  for (int i=0;i<21;i++) key[i] = ~0ULL;
  for (int c = 0; c < WIN; c++) {
    int s = start + c;
    float fm = s_v[s];
    int m = s_i[s];
    float pr = __fmul_rn(fn, fm);
    float dist = __fsub_rn(__fadd_rn(sqn, __fmul_rn(fm, fm)), __fmul_rn(2.0f, pr));
    unsigned u = __float_as_uint(dist);
    u ^= (u >> 31) ? 0xFFFFFFFFu : 0x80000000u;
    unsigned long long kk = (((unsigned long long)u) << 32) | (unsigned)m;
    if (kk < key[20]) {
#pragma unroll
      for (int i=0;i<21;i++) {
        unsigned long long a = key[i];
        bool lt = kk < a;
        unsigned long long mn = lt ? kk : a;
        kk = lt ? a : kk;
        key[i] = mn;
      }
    }
  }
  float* dd = dout + (size_t)(b*NPIX + n)*KN;
#pragma unroll
  for (int i=1;i<=20;i++) {
    int m = (int)(key[i] & 0xFFFFFFFFu);
    dd[i-1] = __fsub_rn(f[b*NPIX + m], fn);   // knn - x1
  }
}

// ---------------- joint moments of (f, d) for BN1 (shared by all branches) ----------------
__global__ __launch_bounds__(256) void stats_k(const float* __restrict__ f,
    const float* __restrict__ dw, double* __restrict__ part) {
  int row = blockIdx.x*256 + threadIdx.x;
  float fv = f[row];
  const float* dd = dw + (size_t)row*KN;
  double sd = 0.0, sdd = 0.0;
#pragma unroll
  for (int k=0;k<KN;k++) { double d = (double)dd[k]; sd += d; sdd += d*d; }
  double q[5];
  q[0] = (double)fv;
  q[1] = (double)fv * (double)fv;
  q[2] = sd;
  q[3] = sdd;
  q[4] = (double)fv * sd;
  __shared__ double sred[4][5];
  int wid = threadIdx.x >> 6, lane = threadIdx.x & 63;
#pragma unroll
  for (int qi=0; qi<5; qi++) {
    double v = q[qi];
    for (int off=32; off>0; off>>=1) v += __shfl_down(v, off, 64);
    if (lane == 0) sred[wid][qi] = v;
  }
  __syncthreads();
  if (threadIdx.x == 0) {
#pragma unroll
    for (int qi=0; qi<5; qi++)
      part[blockIdx.x*5 + qi] = sred[0][qi]+sred[1][qi]+sred[2][qi]+sred[3][qi];
  }
}

// ---------------- fold BN1 into per-channel affine consts A,B,C per branch ----------------
__global__ void finalize1_k(const double* __restrict__ part,
    const float* __restrict__ ew1, const float* __restrict__ eb1,
    const float* __restrict__ eg1, const float* __restrict__ ebt1,
    float* __restrict__ consts1) {
  if (threadIdx.x || blockIdx.x) return;
  double S[5] = {0,0,0,0,0};
  for (int blk=0; blk<64; blk++)
    for (int q=0;q<5;q++) S[q] += part[blk*5+q];
  double Ef = S[0]/16384.0, Eff = S[1]/16384.0;
  double Ed = S[2]/MTOT, Edd = S[3]/MTOT, Efd = S[4]/MTOT;
  double Vf = Eff - Ef*Ef, Vd = Edd - Ed*Ed, Cfd = Efd - Ef*Ed;
  for (int br=0; br<3; br++)
    for (int c=0; c<16; c++) {
      int idx = br*16 + c;
      double w0 = (double)ew1[idx*2+0], w1 = (double)ew1[idx*2+1];
      double b1 = (double)eb1[idx];
      double m1 = w0*Ef + w1*Ed + b1;
      double v1 = w0*w0*Vf + 2.0*w0*w1*Cfd + w1*w1*Vd;
      double r1 = 1.0 / sqrt(v1 + 1e-5);
      double g = (double)eg1[idx];
      consts1[idx*3+0] = (float)(g*r1*w0);
      consts1[idx*3+1] = (float)(g*r1*w1);
      consts1[idx*3+2] = (float)(g*r1*(b1 - m1) + (double)ebt1[idx]);
    }
}

// ---------------- per-branch o_pre: max/min over k + BN2 moments ----------------
__global__ __launch_bounds__(256) void branch_k(const float* __restrict__ f,
    const float* __restrict__ dw, const float* __restrict__ consts1,
    const float* __restrict__ ew2, const float* __restrict__ eb2,
    float* __restrict__ maxo, float* __restrict__ mino,
    double* __restrict__ part2) {
  int br = blockIdx.y;
  __shared__ float sA[16], sB[16], sC[16], sW[16];
  if (threadIdx.x < 16) {
    int idx = br*16 + threadIdx.x;
    sA[threadIdx.x] = consts1[idx*3+0];
    sB[threadIdx.x] = consts1[idx*3+1];
    sC[threadIdx.x] = consts1[idx*3+2];
    sW[threadIdx.x] = ew2[idx];
  }
  __syncthreads();
  int row = blockIdx.x*256 + threadIdx.x;
  float fv = f[row];
  const float* dd = dw + (size_t)row*KN;
  float b2 = eb2[br];
  float P[16];
#pragma unroll
  for (int c=0;c<16;c++) P[c] = fmaf(sA[c], fv, sC[c]);
  float mx = -INFINITY, mn = INFINITY;
  double s = 0.0, s2 = 0.0;
  for (int k=0;k<KN;k++) {
    float d = dd[k];
    float t = b2;
#pragma unroll
    for (int c=0;c<16;c++)
      t = fmaf(sW[c], fmaxf(fmaf(sB[c], d, P[c]), 0.f), t);
    mx = fmaxf(mx, t);
    mn = fminf(mn, t);
    double td = (double)t;
    s += td; s2 += td*td;
  }
  maxo[br*NROWS + row] = mx;
  mino[br*NROWS + row] = mn;
  __shared__ double sred[4][2];
  int wid = threadIdx.x >> 6, lane = threadIdx.x & 63;
  double v0 = s, v1 = s2;
  for (int off=32; off>0; off>>=1) {
    v0 += __shfl_down(v0, off, 64);
    v1 += __shfl_down(v1, off, 64);
  }
  if (lane == 0) { sred[wid][0] = v0; sred[wid][1] = v1; }
  __syncthreads();
  if (threadIdx.x == 0) {
    part2[(br*64 + blockIdx.x)*2 + 0] = sred[0][0]+sred[1][0]+sred[2][0]+sred[3][0];
    part2[(br*64 + blockIdx.x)*2 + 1] = sred[0][1]+sred[1][1]+sred[2][1]+sred[3][1];
  }
}

// ---------------- BN2 constants per branch ----------------
__global__ void finalize2_k(const double* __restrict__ part2,
    const float* __restrict__ eg2, const float* __restrict__ ebt2,
    float* __restrict__ consts2) {
  if (threadIdx.x || blockIdx.x) return;
  for (int br=0; br<3; br++) {
    double s=0, s2=0;
    for (int blk=0; blk<64; blk++) {
      s  += part2[(br*64+blk)*2+0];
      s2 += part2[(br*64+blk)*2+1];
    }
    double mean = s / MTOT;
    double var = s2 / MTOT - mean*mean;
    double r2 = 1.0 / sqrt(var + 1e-5);
    double sc = (double)eg2[br] * r2;
    consts2[br*2+0] = (float)sc;
    consts2[br*2+1] = (float)((double)ebt2[br] - sc*mean);
  }
}

// ---------------- pixel shuffle + sigmoid ----------------
__global__ __launch_bounds__(256) void out_k(const float* __restrict__ f,
    const float* __restrict__ maxo, const float* __restrict__ mino,
    const float* __restrict__ consts2, float* __restrict__ out) {
  int tid = blockIdx.x*256 + threadIdx.x;   // 65536
  int b = tid >> 14;
  int y = (tid >> 7) & 127, xx = tid & 127;
  int n = ((y>>1)<<6) + (xx>>1);
  int ch = ((y&1)<<1) + (xx&1);
  float v;
  if (ch == 0) {
    v = f[b*NPIX + n];
  } else {
    int br = ch - 1;
    float sc = consts2[br*2+0], sh = consts2[br*2+1];
    float base = (sc >= 0.f) ? maxo[br*NROWS + b*NPIX + n]
                             : mino[br*NROWS + b*NPIX + n];
    v = fmaxf(fmaf(sc, base, sh), 0.f);
  }
  out[tid] = 1.f / (1.f + expf(-v));
}

extern "C" void kernel_launch(void* const* d_in, const int* in_sizes, int n_in,
                              void* d_out, int out_size, void* d_ws, size_t ws_size,
                              hipStream_t stream) {
  (void)in_sizes; (void)n_in; (void)out_size; (void)ws_size;
  const float* x    = (const float*)d_in[0];
  const float* c1w  = (const float*)d_in[1];
  const float* c1b  = (const float*)d_in[2];
  const float* c2w  = (const float*)d_in[3];
  const float* c2b  = (const float*)d_in[4];
  const float* c3w  = (const float*)d_in[5];
  const float* c3b  = (const float*)d_in[6];
  const float* c4w  = (const float*)d_in[7];
  const float* c4b  = (const float*)d_in[8];
  const float* ew1  = (const float*)d_in[9];
  const float* eb1  = (const float*)d_in[10];
  const float* eg1  = (const float*)d_in[11];
  const float* ebt1 = (const float*)d_in[12];
  const float* ew2  = (const float*)d_in[13];
  const float* eb2  = (const float*)d_in[14];
  const float* eg2  = (const float*)d_in[15];
  const float* ebt2 = (const float*)d_in[16];
  float* out = (float*)d_out;

  float* c1      = (float*)d_ws;             // 1048576 floats
  float* c2      = c1 + 1048576;             // 524288
  float* c3      = c2 + 524288;              // 262144
  float* fbuf    = c3 + 262144;              // 16384
  float* dw      = fbuf + 16384;             // 327680
  double* part1  = (double*)(dw + 327680);   // 320
  float* consts1 = (float*)(part1 + 320);    // 144
  double* part2  = (double*)(consts1 + 144); // 384
  float* maxo    = (float*)(part2 + 384);    // 49152
  float* mino    = maxo + 49152;             // 49152
  float* consts2 = mino + 49152;             // 6 (+pad 2)
  float* svalw   = consts2 + 8;              // 16384
  int*   sidxw   = (int*)(svalw + 16384);    // 16384
  int*   rankw   = sidxw + 16384;            // 16384

  conv1_k<<<dim3(4,64), 256, 0, stream>>>(x, c1w, c1b, c1);
  conv3x3_k<64,16,true ><<<dim3(4,16,2), 256, 0, stream>>>(c1, c2w, c2b, c2, 32);
  conv3x3_k<32,16,true ><<<dim3(4,16,1), 256, 0, stream>>>(c2, c3w, c3b, c3, 16);
  conv3x3_k<16, 1,false><<<dim3(4,16,1), 256, 0, stream>>>(c3, c4w, c4b, fbuf, 1);
  sort_k<<<4, 1024, 0, stream>>>(fbuf, svalw, sidxw, rankw);
  knn2_k<<<64, 256, 0, stream>>>(fbuf, svalw, sidxw, rankw, dw);
  stats_k<<<64, 256, 0, stream>>>(fbuf, dw, part1);
  finalize1_k<<<1, 64, 0, stream>>>(part1, ew1, eb1, eg1, ebt1, consts1);
  branch_k<<<dim3(64,3), 256, 0, stream>>>(fbuf, dw, consts1, ew2, eb2, maxo, mino, part2);
  finalize2_k<<<1, 64, 0, stream>>>(part2, eg2, ebt2, consts2);
  out_k<<<256, 256, 0, stream>>>(fbuf, maxo, mino, consts2, out);
}

// Round 3
// 203.175 us; speedup vs baseline: 12.8425x; 1.5667x over previous
//
#include <hip/hip_runtime.h>
#include <math.h>

#define NPIX 4096
#define NROWS 16384      // B*N
#define KN 20
#define WIN 65           // sorted-order candidate window (32 each side + self)
#define MTOT 327680.0    // B*N*K

// ---------------- conv1: 5x5, 1->64, pad 2, tanh ----------------
__global__ __launch_bounds__(256) void conv1_k(const float* __restrict__ x,
    const float* __restrict__ w, const float* __restrict__ bias,
    float* __restrict__ out) {
  int b = blockIdx.x, co = blockIdx.y;
  __shared__ float tile[68*68];
  __shared__ float wt[25];
  const float* src = x + b*NPIX;
  for (int i = threadIdx.x; i < 68*68; i += 256) {
    int r = i/68 - 2, c = i%68 - 2;
    tile[i] = (r>=0 && r<64 && c>=0 && c<64) ? src[r*64+c] : 0.f;
  }
  if (threadIdx.x < 25) wt[threadIdx.x] = w[co*25 + threadIdx.x];
  __syncthreads();
  float bv = bias[co];
  for (int p = threadIdx.x; p < NPIX; p += 256) {
    int r = p >> 6, c = p & 63;
    float acc = bv;
#pragma unroll
    for (int di=0; di<5; di++)
#pragma unroll
      for (int dj=0; dj<5; dj++)
        acc = fmaf(tile[(r+di)*68 + c+dj], wt[di*5+dj], acc);
    out[(b*64+co)*NPIX + p] = tanhf(acc);
  }
}

// ---------------- 3x3 conv, all-cin single-stage, 8x8 tile ----------------
// 256 threads = 64 pixels x 4 cout-groups (OC couts each).
// Accumulation order per output: cin outer, then tap 0..8 — identical to the
// verified round-2 kernel's rounding.
template<int CIN, int COUT, int OC, bool TANH>
__global__ __launch_bounds__(256) void conv3x3b_k(const float* __restrict__ in,
    const float* __restrict__ w, const float* __restrict__ bias,
    float* __restrict__ out) {
  int b = blockIdx.x, tile = blockIdx.y;
  int th = (tile >> 3) << 3, tw = (tile & 7) << 3;
  __shared__ float s_in[CIN*120];           // CIN x 10 x stride12
  for (int i = threadIdx.x; i < CIN*100; i += 256) {
    int cin = i / 100, rem = i - cin*100;
    int r = rem / 10, c = rem - r*10;
    int gr = th + r - 1, gc = tw + c - 1;
    float v = 0.f;
    if (gr >= 0 && gr < 64 && gc >= 0 && gc < 64)
      v = in[(((size_t)b*CIN + cin) << 12) + (gr << 6) + gc];
    s_in[cin*120 + r*12 + c] = v;
  }
  __syncthreads();
  int pix = threadIdx.x & 63;
  int py = pix >> 3, px = pix & 7;
  int og = __builtin_amdgcn_readfirstlane(threadIdx.x >> 6);  // wave-uniform
  const float* wb = w + og*OC*CIN*9;
  const float* bb = bias + og*OC;
  float acc[OC];
#pragma unroll
  for (int o=0;o<OC;o++) acc[o] = bb[o];
  for (int cin = 0; cin < CIN; cin++) {
    float v[9];
#pragma unroll
    for (int di=0;di<3;di++)
#pragma unroll
      for (int dj=0;dj<3;dj++)
        v[di*3+dj] = s_in[cin*120 + (py+di)*12 + px+dj];
    const float* wc = wb + cin*9;
#pragma unroll
    for (int o=0;o<OC;o++)
#pragma unroll
      for (int t=0;t<9;t++)
        acc[o] = fmaf(v[t], wc[o*CIN*9 + t], acc[o]);
  }
#pragma unroll
  for (int o=0;o<OC;o++) {
    float r = TANH ? tanhf(acc[o]) : acc[o];
    out[(((size_t)b*COUT + og*OC + o) << 12) + ((th+py)<<6) + (tw+px)] = r;
  }
}

// ---------------- conv4: 3x3, 16->1, no activation, 16x16 tile ----------------
// One thread per pixel; sequential cin 0..15 — identical rounding to round-2.
__global__ __launch_bounds__(256) void conv4_k(const float* __restrict__ in,
    const float* __restrict__ w, const float* __restrict__ bias,
    float* __restrict__ out) {
  int b = blockIdx.x, tile = blockIdx.y;
  int th = (tile >> 2) << 4, tw = (tile & 3) << 4;
  __shared__ float s_in[16*18*20];          // 16 x 18 x stride20
  for (int i = threadIdx.x; i < 16*324; i += 256) {
    int cin = i / 324, rem = i - cin*324;
    int r = rem / 18, c = rem - r*18;
    int gr = th + r - 1, gc = tw + c - 1;
    float v = 0.f;
    if (gr >= 0 && gr < 64 && gc >= 0 && gc < 64)
      v = in[(((size_t)b*16 + cin) << 12) + (gr << 6) + gc];
    s_in[cin*360 + r*20 + c] = v;
  }
  __syncthreads();
  int ty = threadIdx.x >> 4, tx = threadIdx.x & 15;
  float acc = bias[0];
  for (int cin = 0; cin < 16; cin++) {
#pragma unroll
    for (int di=0;di<3;di++)
#pragma unroll
      for (int dj=0;dj<3;dj++)
        acc = fmaf(s_in[cin*360 + (ty+di)*20 + tx+dj], w[cin*9 + di*3+dj], acc);
  }
  out[((size_t)b << 12) + ((th+ty)<<6) + (tw+tx)] = acc;
}

// ---------------- per-batch bitonic sort of (value, idx) ----------------
__global__ __launch_bounds__(1024) void sort_k(const float* __restrict__ f,
    float* __restrict__ sval, int* __restrict__ sidx, int* __restrict__ rank) {
  int b = blockIdx.x;
  __shared__ unsigned long long skey[NPIX];
  const float* fb = f + b*NPIX;
  for (int i = threadIdx.x; i < NPIX; i += 1024) {
    float v = fb[i];
    unsigned u = __float_as_uint(v);
    u ^= (u >> 31) ? 0xFFFFFFFFu : 0x80000000u;   // order-preserving flip
    skey[i] = (((unsigned long long)u) << 32) | (unsigned)i;
  }
  __syncthreads();
  for (int k = 2; k <= NPIX; k <<= 1) {
    for (int j = k >> 1; j > 0; j >>= 1) {
      for (int i = threadIdx.x; i < NPIX; i += 1024) {
        int p = i ^ j;
        if (p > i) {
          unsigned long long a = skey[i], c = skey[p];
          bool asc = ((i & k) == 0);
          if ((a > c) == asc) { skey[i] = c; skey[p] = a; }
        }
      }
      __syncthreads();
    }
  }
  for (int s = threadIdx.x; s < NPIX; s += 1024) {
    int idx = (int)(skey[s] & 0xFFFFFFFFu);
    sval[b*NPIX + s] = fb[idx];
    sidx[b*NPIX + s] = idx;
    rank[b*NPIX + idx] = s;
  }
}

// ---------------- KNN over sorted-order window ----------------
__global__ __launch_bounds__(256) void knn2_k(const float* __restrict__ f,
    const float* __restrict__ sval, const int* __restrict__ sidx,
    const int* __restrict__ rank, float* __restrict__ dout) {
  int b = blockIdx.x >> 4, grp = blockIdx.x & 15;
  __shared__ float s_v[NPIX];
  __shared__ int   s_i[NPIX];
  const float* svb = sval + b*NPIX;
  const int*   sib = sidx + b*NPIX;
  for (int i = threadIdx.x; i < NPIX; i += 256) {
    s_v[i] = svb[i];
    s_i[i] = sib[i];
  }
  __syncthreads();
  int n = (grp << 8) + threadIdx.x;
  int p = rank[b*NPIX + n];
  float fn = f[b*NPIX + n];
  float sqn = __fmul_rn(fn, fn);
  int start = p - 32;
  if (start < 0) start = 0;
  if (start > NPIX - WIN) start = NPIX - WIN;
  unsigned long long key[21];
#pragma unroll
  for (int i=0;i<21;i++) key[i] = ~0ULL;
  for (int c = 0; c < WIN; c++) {
    int s = start + c;
    float fm = s_v[s];
    int m = s_i[s];
    float pr = __fmul_rn(fn, fm);
    float dist = __fsub_rn(__fadd_rn(sqn, __fmul_rn(fm, fm)), __fmul_rn(2.0f, pr));
    unsigned u = __float_as_uint(dist);
    u ^= (u >> 31) ? 0xFFFFFFFFu : 0x80000000u;
    unsigned long long kk = (((unsigned long long)u) << 32) | (unsigned)m;
    if (kk < key[20]) {
#pragma unroll
      for (int i=0;i<21;i++) {
        unsigned long long a = key[i];
        bool lt = kk < a;
        unsigned long long mn = lt ? kk : a;
        kk = lt ? a : kk;
        key[i] = mn;
      }
    }
  }
  float* dd = dout + (size_t)(b*NPIX + n)*KN;
#pragma unroll
  for (int i=1;i<=20;i++) {
    int m = (int)(key[i] & 0xFFFFFFFFu);
    dd[i-1] = __fsub_rn(f[b*NPIX + m], fn);   // knn - x1
  }
}

// ---------------- joint moments of (f, d) for BN1 ----------------
__global__ __launch_bounds__(256) void stats_k(const float* __restrict__ f,
    const float* __restrict__ dw, double* __restrict__ part) {
  int row = blockIdx.x*256 + threadIdx.x;
  float fv = f[row];
  const float* dd = dw + (size_t)row*KN;
  double sd = 0.0, sdd = 0.0;
#pragma unroll
  for (int k=0;k<KN;k++) { double d = (double)dd[k]; sd += d; sdd += d*d; }
  double q[5];
  q[0] = (double)fv;
  q[1] = (double)fv * (double)fv;
  q[2] = sd;
  q[3] = sdd;
  q[4] = (double)fv * sd;
  __shared__ double sred[4][5];
  int wid = threadIdx.x >> 6, lane = threadIdx.x & 63;
#pragma unroll
  for (int qi=0; qi<5; qi++) {
    double v = q[qi];
    for (int off=32; off>0; off>>=1) v += __shfl_down(v, off, 64);
    if (lane == 0) sred[wid][qi] = v;
  }
  __syncthreads();
  if (threadIdx.x == 0) {
#pragma unroll
    for (int qi=0; qi<5; qi++)
      part[blockIdx.x*5 + qi] = sred[0][qi]+sred[1][qi]+sred[2][qi]+sred[3][qi];
  }
}

// ---------------- fold BN1 into per-channel affine consts ----------------
__global__ void finalize1_k(const double* __restrict__ part,
    const float* __restrict__ ew1, const float* __restrict__ eb1,
    const float* __restrict__ eg1, const float* __restrict__ ebt1,
    float* __restrict__ consts1) {
  if (threadIdx.x || blockIdx.x) return;
  double S[5] = {0,0,0,0,0};
  for (int blk=0; blk<64; blk++)
    for (int q=0;q<5;q++) S[q] += part[blk*5+q];
  double Ef = S[0]/16384.0, Eff = S[1]/16384.0;
  double Ed = S[2]/MTOT, Edd = S[3]/MTOT, Efd = S[4]/MTOT;
  double Vf = Eff - Ef*Ef, Vd = Edd - Ed*Ed, Cfd = Efd - Ef*Ed;
  for (int br=0; br<3; br++)
    for (int c=0; c<16; c++) {
      int idx = br*16 + c;
      double w0 = (double)ew1[idx*2+0], w1 = (double)ew1[idx*2+1];
      double b1 = (double)eb1[idx];
      double m1 = w0*Ef + w1*Ed + b1;
      double v1 = w0*w0*Vf + 2.0*w0*w1*Cfd + w1*w1*Vd;
      double r1 = 1.0 / sqrt(v1 + 1e-5);
      double g = (double)eg1[idx];
      consts1[idx*3+0] = (float)(g*r1*w0);
      consts1[idx*3+1] = (float)(g*r1*w1);
      consts1[idx*3+2] = (float)(g*r1*(b1 - m1) + (double)ebt1[idx]);
    }
}

// ---------------- per-branch o_pre: max/min over k + BN2 moments ----------------
__global__ __launch_bounds__(256) void branch_k(const float* __restrict__ f,
    const float* __restrict__ dw, const float* __restrict__ consts1,
    const float* __restrict__ ew2, const float* __restrict__ eb2,
    float* __restrict__ maxo, float* __restrict__ mino,
    double* __restrict__ part2) {
  int br = blockIdx.y;
  __shared__ float sA[16], sB[16], sC[16], sW[16];
  if (threadIdx.x < 16) {
    int idx = br*16 + threadIdx.x;
    sA[threadIdx.x] = consts1[idx*3+0];
    sB[threadIdx.x] = consts1[idx*3+1];
    sC[threadIdx.x] = consts1[idx*3+2];
    sW[threadIdx.x] = ew2[idx];
  }
  __syncthreads();
  int row = blockIdx.x*256 + threadIdx.x;
  float fv = f[row];
  const float* dd = dw + (size_t)row*KN;
  float b2 = eb2[br];
  float P[16];
#pragma unroll
  for (int c=0;c<16;c++) P[c] = fmaf(sA[c], fv, sC[c]);
  float mx = -INFINITY, mn = INFINITY;
  double s = 0.0, s2 = 0.0;
  for (int k=0;k<KN;k++) {
    float d = dd[k];
    float t = b2;
#pragma unroll
    for (int c=0;c<16;c++)
      t = fmaf(sW[c], fmaxf(fmaf(sB[c], d, P[c]), 0.f), t);
    mx = fmaxf(mx, t);
    mn = fminf(mn, t);
    double td = (double)t;
    s += td; s2 += td*td;
  }
  maxo[br*NROWS + row] = mx;
  mino[br*NROWS + row] = mn;
  __shared__ double sred[4][2];
  int wid = threadIdx.x >> 6, lane = threadIdx.x & 63;
  double v0 = s, v1 = s2;
  for (int off=32; off>0; off>>=1) {
    v0 += __shfl_down(v0, off, 64);
    v1 += __shfl_down(v1, off, 64);
  }
  if (lane == 0) { sred[wid][0] = v0; sred[wid][1] = v1; }
  __syncthreads();
  if (threadIdx.x == 0) {
    part2[(br*64 + blockIdx.x)*2 + 0] = sred[0][0]+sred[1][0]+sred[2][0]+sred[3][0];
    part2[(br*64 + blockIdx.x)*2 + 1] = sred[0][1]+sred[1][1]+sred[2][1]+sred[3][1];
  }
}

// ---------------- BN2 constants per branch ----------------
__global__ void finalize2_k(const double* __restrict__ part2,
    const float* __restrict__ eg2, const float* __restrict__ ebt2,
    float* __restrict__ consts2) {
  if (threadIdx.x || blockIdx.x) return;
  for (int br=0; br<3; br++) {
    double s=0, s2=0;
    for (int blk=0; blk<64; blk++) {
      s  += part2[(br*64+blk)*2+0];
      s2 += part2[(br*64+blk)*2+1];
    }
    double mean = s / MTOT;
    double var = s2 / MTOT - mean*mean;
    double r2 = 1.0 / sqrt(var + 1e-5);
    double sc = (double)eg2[br] * r2;
    consts2[br*2+0] = (float)sc;
    consts2[br*2+1] = (float)((double)ebt2[br] - sc*mean);
  }
}

// ---------------- pixel shuffle + sigmoid ----------------
__global__ __launch_bounds__(256) void out_k(const float* __restrict__ f,
    const float* __restrict__ maxo, const float* __restrict__ mino,
    const float* __restrict__ consts2, float* __restrict__ out) {
  int tid = blockIdx.x*256 + threadIdx.x;   // 65536
  int b = tid >> 14;
  int y = (tid >> 7) & 127, xx = tid & 127;
  int n = ((y>>1)<<6) + (xx>>1);
  int ch = ((y&1)<<1) + (xx&1);
  float v;
  if (ch == 0) {
    v = f[b*NPIX + n];
  } else {
    int br = ch - 1;
    float sc = consts2[br*2+0], sh = consts2[br*2+1];
    float base = (sc >= 0.f) ? maxo[br*NROWS + b*NPIX + n]
                             : mino[br*NROWS + b*NPIX + n];
    v = fmaxf(fmaf(sc, base, sh), 0.f);
  }
  out[tid] = 1.f / (1.f + expf(-v));
}

extern "C" void kernel_launch(void* const* d_in, const int* in_sizes, int n_in,
                              void* d_out, int out_size, void* d_ws, size_t ws_size,
                              hipStream_t stream) {
  (void)in_sizes; (void)n_in; (void)out_size; (void)ws_size;
  const float* x    = (const float*)d_in[0];
  const float* c1w  = (const float*)d_in[1];
  const float* c1b  = (const float*)d_in[2];
  const float* c2w  = (const float*)d_in[3];
  const float* c2b  = (const float*)d_in[4];
  const float* c3w  = (const float*)d_in[5];
  const float* c3b  = (const float*)d_in[6];
  const float* c4w  = (const float*)d_in[7];
  const float* c4b  = (const float*)d_in[8];
  const float* ew1  = (const float*)d_in[9];
  const float* eb1  = (const float*)d_in[10];
  const float* eg1  = (const float*)d_in[11];
  const float* ebt1 = (const float*)d_in[12];
  const float* ew2  = (const float*)d_in[13];
  const float* eb2  = (const float*)d_in[14];
  const float* eg2  = (const float*)d_in[15];
  const float* ebt2 = (const float*)d_in[16];
  float* out = (float*)d_out;

  float* c1      = (float*)d_ws;             // 1048576 floats
  float* c2      = c1 + 1048576;             // 524288
  float* c3      = c2 + 524288;              // 262144
  float* fbuf    = c3 + 262144;              // 16384
  float* dw      = fbuf + 16384;             // 327680
  double* part1  = (double*)(dw + 327680);   // 320
  float* consts1 = (float*)(part1 + 320);    // 144
  double* part2  = (double*)(consts1 + 144); // 384
  float* maxo    = (float*)(part2 + 384);    // 49152
  float* mino    = maxo + 49152;             // 49152
  float* consts2 = mino + 49152;             // 6 (+pad 2)
  float* svalw   = consts2 + 8;              // 16384
  int*   sidxw   = (int*)(svalw + 16384);    // 16384
  int*   rankw   = sidxw + 16384;            // 16384

  conv1_k<<<dim3(4,64), 256, 0, stream>>>(x, c1w, c1b, c1);
  conv3x3b_k<64,32,8,true ><<<dim3(4,64), 256, 0, stream>>>(c1, c2w, c2b, c2);
  conv3x3b_k<32,16,4,true ><<<dim3(4,64), 256, 0, stream>>>(c2, c3w, c3b, c3);
  conv4_k<<<dim3(4,16), 256, 0, stream>>>(c3, c4w, c4b, fbuf);
  sort_k<<<4, 1024, 0, stream>>>(fbuf, svalw, sidxw, rankw);
  knn2_k<<<64, 256, 0, stream>>>(fbuf, svalw, sidxw, rankw, dw);
  stats_k<<<64, 256, 0, stream>>>(fbuf, dw, part1);
  finalize1_k<<<1, 64, 0, stream>>>(part1, ew1, eb1, eg1, ebt1, consts1);
  branch_k<<<dim3(64,3), 256, 0, stream>>>(fbuf, dw, consts1, ew2, eb2, maxo, mino, part2);
  finalize2_k<<<1, 64, 0, stream>>>(part2, eg2, ebt2, consts2);
  out_k<<<256, 256, 0, stream>>>(fbuf, maxo, mino, consts2, out);
}

// Round 4
// 185.730 us; speedup vs baseline: 14.0488x; 1.0939x over previous
//
#include <hip/hip_runtime.h>
#include <math.h>

#define NPIX 4096
#define NROWS 16384      // B*N
#define KN 20
#define WIN 65           // sorted-order candidate window (32 each side + self)
#define MTOT 327680.0    // B*N*K

// ---------------- conv1: 5x5, 1->64, pad 2, tanh ----------------
__global__ __launch_bounds__(256) void conv1_k(const float* __restrict__ x,
    const float* __restrict__ w, const float* __restrict__ bias,
    float* __restrict__ out) {
  int b = blockIdx.x, co = blockIdx.y;
  __shared__ float tile[68*68];
  __shared__ float wt[25];
  const float* src = x + b*NPIX;
  for (int i = threadIdx.x; i < 68*68; i += 256) {
    int r = i/68 - 2, c = i%68 - 2;
    tile[i] = (r>=0 && r<64 && c>=0 && c<64) ? src[r*64+c] : 0.f;
  }
  if (threadIdx.x < 25) wt[threadIdx.x] = w[co*25 + threadIdx.x];
  __syncthreads();
  float bv = bias[co];
  for (int p = threadIdx.x; p < NPIX; p += 256) {
    int r = p >> 6, c = p & 63;
    float acc = bv;
#pragma unroll
    for (int di=0; di<5; di++)
#pragma unroll
      for (int dj=0; dj<5; dj++)
        acc = fmaf(tile[(r+di)*68 + c+dj], wt[di*5+dj], acc);
    out[(b*64+co)*NPIX + p] = tanhf(acc);
  }
}

// ---------------- 3x3 conv, all-cin single-stage, 8x8 tile ----------------
template<int CIN, int COUT, int OC, bool TANH>
__global__ __launch_bounds__(256) void conv3x3b_k(const float* __restrict__ in,
    const float* __restrict__ w, const float* __restrict__ bias,
    float* __restrict__ out) {
  int b = blockIdx.x, tile = blockIdx.y;
  int th = (tile >> 3) << 3, tw = (tile & 7) << 3;
  __shared__ float s_in[CIN*120];           // CIN x 10 x stride12
  for (int i = threadIdx.x; i < CIN*100; i += 256) {
    int cin = i / 100, rem = i - cin*100;
    int r = rem / 10, c = rem - r*10;
    int gr = th + r - 1, gc = tw + c - 1;
    float v = 0.f;
    if (gr >= 0 && gr < 64 && gc >= 0 && gc < 64)
      v = in[(((size_t)b*CIN + cin) << 12) + (gr << 6) + gc];
    s_in[cin*120 + r*12 + c] = v;
  }
  __syncthreads();
  int pix = threadIdx.x & 63;
  int py = pix >> 3, px = pix & 7;
  int og = __builtin_amdgcn_readfirstlane(threadIdx.x >> 6);  // wave-uniform
  const float* wb = w + og*OC*CIN*9;
  const float* bb = bias + og*OC;
  float acc[OC];
#pragma unroll
  for (int o=0;o<OC;o++) acc[o] = bb[o];
  for (int cin = 0; cin < CIN; cin++) {
    float v[9];
#pragma unroll
    for (int di=0;di<3;di++)
#pragma unroll
      for (int dj=0;dj<3;dj++)
        v[di*3+dj] = s_in[cin*120 + (py+di)*12 + px+dj];
    const float* wc = wb + cin*9;
#pragma unroll
    for (int o=0;o<OC;o++)
#pragma unroll
      for (int t=0;t<9;t++)
        acc[o] = fmaf(v[t], wc[o*CIN*9 + t], acc[o]);
  }
#pragma unroll
  for (int o=0;o<OC;o++) {
    float r = TANH ? tanhf(acc[o]) : acc[o];
    out[(((size_t)b*COUT + og*OC + o) << 12) + ((th+py)<<6) + (tw+px)] = r;
  }
}

// ---------------- conv4: 3x3, 16->1, no activation, 16x16 tile ----------------
__global__ __launch_bounds__(256) void conv4_k(const float* __restrict__ in,
    const float* __restrict__ w, const float* __restrict__ bias,
    float* __restrict__ out) {
  int b = blockIdx.x, tile = blockIdx.y;
  int th = (tile >> 2) << 4, tw = (tile & 3) << 4;
  __shared__ float s_in[16*18*20];          // 16 x 18 x stride20
  for (int i = threadIdx.x; i < 16*324; i += 256) {
    int cin = i / 324, rem = i - cin*324;
    int r = rem / 18, c = rem - r*18;
    int gr = th + r - 1, gc = tw + c - 1;
    float v = 0.f;
    if (gr >= 0 && gr < 64 && gc >= 0 && gc < 64)
      v = in[(((size_t)b*16 + cin) << 12) + (gr << 6) + gc];
    s_in[cin*360 + r*20 + c] = v;
  }
  __syncthreads();
  int ty = threadIdx.x >> 4, tx = threadIdx.x & 15;
  float acc = bias[0];
  for (int cin = 0; cin < 16; cin++) {
#pragma unroll
    for (int di=0;di<3;di++)
#pragma unroll
      for (int dj=0;dj<3;dj++)
        acc = fmaf(s_in[cin*360 + (ty+di)*20 + tx+dj], w[cin*9 + di*3+dj], acc);
  }
  out[((size_t)b << 12) + ((th+ty)<<6) + (tw+tx)] = acc;
}

// ---------------- register-blocked bitonic sort (per batch) ----------------
// 1024 threads x 4 keys. Element e = wave*256 + r*64 + lane.
//   j<=32  : __shfl_xor within wave (no barrier)  [57 stages]
//   j=64/128: intra-thread register exchange       [11 stages]
//   j>=256 : double-buffered LDS, 1 barrier/stage  [10 stages]
// Produces the identical stable order as a full u64 (value||idx) sort.
__device__ inline unsigned long long shflx64(unsigned long long v, int m) {
  unsigned lo = (unsigned)v, hi = (unsigned)(v >> 32);
  lo = __shfl_xor(lo, m, 64);
  hi = __shfl_xor(hi, m, 64);
  return (((unsigned long long)hi) << 32) | lo;
}

__global__ __launch_bounds__(1024) void sort_k(const float* __restrict__ f,
    float* __restrict__ sval, int* __restrict__ sidx, int* __restrict__ rank) {
  int b = blockIdx.x;
  int l = threadIdx.x & 63;
  int w = threadIdx.x >> 6;
  __shared__ unsigned long long lds0[NPIX];
  __shared__ unsigned long long lds1[NPIX];
  const float* fb = f + b*NPIX;
  unsigned long long key[4];
#pragma unroll
  for (int r=0;r<4;r++) {
    unsigned e = (w<<8) + (r<<6) + l;
    float v = fb[e];
    unsigned u = __float_as_uint(v);
    u ^= (u >> 31) ? 0xFFFFFFFFu : 0x80000000u;   // order-preserving flip
    key[r] = (((unsigned long long)u) << 32) | e;
  }
  int bufsel = 0;
  for (unsigned k = 2; k <= 4096; k <<= 1) {
    for (unsigned j = k >> 1; j > 0; j >>= 1) {
      if (j >= 256) {
        unsigned long long* buf = bufsel ? lds1 : lds0;
        bufsel ^= 1;
#pragma unroll
        for (int r=0;r<4;r++) buf[(w<<8)+(r<<6)+l] = key[r];
        __syncthreads();
#pragma unroll
        for (int r=0;r<4;r++) {
          unsigned e = (w<<8)+(r<<6)+l;
          unsigned long long a = key[r];
          unsigned long long p = buf[e ^ j];
          bool up = ((e & k) == 0);
          bool keepmin = ((e & j) == 0) == up;
          bool sw = keepmin ? (p < a) : (p > a);
          key[r] = sw ? p : a;
        }
      } else if (j >= 64) {
        unsigned rj = j >> 6;
#pragma unroll
        for (int r=0;r<4;r++) {
          int pr = r ^ (int)rj;
          if (pr > r) {
            unsigned e = (w<<8)+((unsigned)r<<6)+l;
            bool up = ((e & k) == 0);
            unsigned long long a = key[r], c = key[pr];
            bool sw = up ? (c < a) : (c > a);
            if (sw) { key[r] = c; key[pr] = a; }
          }
        }
      } else {
#pragma unroll
        for (int r=0;r<4;r++) {
          unsigned e = (w<<8)+((unsigned)r<<6)+l;
          unsigned long long a = key[r];
          unsigned long long p = shflx64(a, (int)j);
          bool up = ((e & k) == 0);
          bool keepmin = ((e & j) == 0) == up;
          bool sw = keepmin ? (p < a) : (p > a);
          key[r] = sw ? p : a;
        }
      }
    }
  }
#pragma unroll
  for (int r=0;r<4;r++) {
    unsigned e = (w<<8)+((unsigned)r<<6)+l;    // sorted position
    int idx = (int)(key[r] & 0xFFFFFFFFu);
    sval[b*NPIX + e] = fb[idx];
    sidx[b*NPIX + e] = idx;
    rank[b*NPIX + idx] = (int)e;
  }
}

// ---------------- KNN over sorted-order window + fused BN1 moments ----------------
// Same block/thread->row mapping and reduction order as the old stats_k:
// bit-identical part sums.
__global__ __launch_bounds__(256) void knn2_k(const float* __restrict__ f,
    const float* __restrict__ sval, const int* __restrict__ sidx,
    const int* __restrict__ rank, float* __restrict__ dout,
    double* __restrict__ part) {
  int b = blockIdx.x >> 4, grp = blockIdx.x & 15;
  __shared__ float s_v[NPIX];
  __shared__ int   s_i[NPIX];
  const float* svb = sval + b*NPIX;
  const int*   sib = sidx + b*NPIX;
  for (int i = threadIdx.x; i < NPIX; i += 256) {
    s_v[i] = svb[i];
    s_i[i] = sib[i];
  }
  __syncthreads();
  int n = (grp << 8) + threadIdx.x;
  int p = rank[b*NPIX + n];
  float fn = f[b*NPIX + n];
  float sqn = __fmul_rn(fn, fn);
  int start = p - 32;
  if (start < 0) start = 0;
  if (start > NPIX - WIN) start = NPIX - WIN;
  unsigned long long key[21];
#pragma unroll
  for (int i=0;i<21;i++) key[i] = ~0ULL;
  for (int c = 0; c < WIN; c++) {
    int s = start + c;
    float fm = s_v[s];
    int m = s_i[s];
    float pr = __fmul_rn(fn, fm);
    float dist = __fsub_rn(__fadd_rn(sqn, __fmul_rn(fm, fm)), __fmul_rn(2.0f, pr));
    unsigned u = __float_as_uint(dist);
    u ^= (u >> 31) ? 0xFFFFFFFFu : 0x80000000u;
    unsigned long long kk = (((unsigned long long)u) << 32) | (unsigned)m;
    if (kk < key[20]) {
#pragma unroll
      for (int i=0;i<21;i++) {
        unsigned long long a = key[i];
        bool lt = kk < a;
        unsigned long long mn = lt ? kk : a;
        kk = lt ? a : kk;
        key[i] = mn;
      }
    }
  }
  float* dd = dout + (size_t)(b*NPIX + n)*KN;
  double sd = 0.0, sdd = 0.0;
#pragma unroll
  for (int i=1;i<=20;i++) {
    int m = (int)(key[i] & 0xFFFFFFFFu);
    float d = __fsub_rn(f[b*NPIX + m], fn);   // knn - x1
    dd[i-1] = d;
    double db = (double)d;
    sd += db; sdd += db*db;
  }
  double q[5];
  q[0] = (double)fn;
  q[1] = (double)fn * (double)fn;
  q[2] = sd;
  q[3] = sdd;
  q[4] = (double)fn * sd;
  __shared__ double sred[4][5];
  int wid = threadIdx.x >> 6, lane = threadIdx.x & 63;
#pragma unroll
  for (int qi=0; qi<5; qi++) {
    double v = q[qi];
    for (int off=32; off>0; off>>=1) v += __shfl_down(v, off, 64);
    if (lane == 0) sred[wid][qi] = v;
  }
  __syncthreads();
  if (threadIdx.x == 0) {
#pragma unroll
    for (int qi=0; qi<5; qi++)
      part[blockIdx.x*5 + qi] = sred[0][qi]+sred[1][qi]+sred[2][qi]+sred[3][qi];
  }
}

// ---------------- fold BN1 into per-channel affine consts ----------------
__global__ void finalize1_k(const double* __restrict__ part,
    const float* __restrict__ ew1, const float* __restrict__ eb1,
    const float* __restrict__ eg1, const float* __restrict__ ebt1,
    float* __restrict__ consts1) {
  if (threadIdx.x || blockIdx.x) return;
  double S[5] = {0,0,0,0,0};
  for (int blk=0; blk<64; blk++)
    for (int q=0;q<5;q++) S[q] += part[blk*5+q];
  double Ef = S[0]/16384.0, Eff = S[1]/16384.0;
  double Ed = S[2]/MTOT, Edd = S[3]/MTOT, Efd = S[4]/MTOT;
  double Vf = Eff - Ef*Ef, Vd = Edd - Ed*Ed, Cfd = Efd - Ef*Ed;
  for (int br=0; br<3; br++)
    for (int c=0; c<16; c++) {
      int idx = br*16 + c;
      double w0 = (double)ew1[idx*2+0], w1 = (double)ew1[idx*2+1];
      double b1 = (double)eb1[idx];
      double m1 = w0*Ef + w1*Ed + b1;
      double v1 = w0*w0*Vf + 2.0*w0*w1*Cfd + w1*w1*Vd;
      double r1 = 1.0 / sqrt(v1 + 1e-5);
      double g = (double)eg1[idx];
      consts1[idx*3+0] = (float)(g*r1*w0);
      consts1[idx*3+1] = (float)(g*r1*w1);
      consts1[idx*3+2] = (float)(g*r1*(b1 - m1) + (double)ebt1[idx]);
    }
}

// ---------------- per-branch o_pre: max/min over k + BN2 moments ----------------
__global__ __launch_bounds__(256) void branch_k(const float* __restrict__ f,
    const float* __restrict__ dw, const float* __restrict__ consts1,
    const float* __restrict__ ew2, const float* __restrict__ eb2,
    float* __restrict__ maxo, float* __restrict__ mino,
    double* __restrict__ part2) {
  int br = blockIdx.y;
  __shared__ float sA[16], sB[16], sC[16], sW[16];
  if (threadIdx.x < 16) {
    int idx = br*16 + threadIdx.x;
    sA[threadIdx.x] = consts1[idx*3+0];
    sB[threadIdx.x] = consts1[idx*3+1];
    sC[threadIdx.x] = consts1[idx*3+2];
    sW[threadIdx.x] = ew2[idx];
  }
  __syncthreads();
  int row = blockIdx.x*256 + threadIdx.x;
  float fv = f[row];
  const float* dd = dw + (size_t)row*KN;
  float b2 = eb2[br];
  float P[16];
#pragma unroll
  for (int c=0;c<16;c++) P[c] = fmaf(sA[c], fv, sC[c]);
  float mx = -INFINITY, mn = INFINITY;
  double s = 0.0, s2 = 0.0;
  for (int k=0;k<KN;k++) {
    float d = dd[k];
    float t = b2;
#pragma unroll
    for (int c=0;c<16;c++)
      t = fmaf(sW[c], fmaxf(fmaf(sB[c], d, P[c]), 0.f), t);
    mx = fmaxf(mx, t);
    mn = fminf(mn, t);
    double td = (double)t;
    s += td; s2 += td*td;
  }
  maxo[br*NROWS + row] = mx;
  mino[br*NROWS + row] = mn;
  __shared__ double sred[4][2];
  int wid = threadIdx.x >> 6, lane = threadIdx.x & 63;
  double v0 = s, v1 = s2;
  for (int off=32; off>0; off>>=1) {
    v0 += __shfl_down(v0, off, 64);
    v1 += __shfl_down(v1, off, 64);
  }
  if (lane == 0) { sred[wid][0] = v0; sred[wid][1] = v1; }
  __syncthreads();
  if (threadIdx.x == 0) {
    part2[(br*64 + blockIdx.x)*2 + 0] = sred[0][0]+sred[1][0]+sred[2][0]+sred[3][0];
    part2[(br*64 + blockIdx.x)*2 + 1] = sred[0][1]+sred[1][1]+sred[2][1]+sred[3][1];
  }
}

// ---------------- BN2 constants per branch ----------------
__global__ void finalize2_k(const double* __restrict__ part2,
    const float* __restrict__ eg2, const float* __restrict__ ebt2,
    float* __restrict__ consts2) {
  if (threadIdx.x || blockIdx.x) return;
  for (int br=0; br<3; br++) {
    double s=0, s2=0;
    for (int blk=0; blk<64; blk++) {
      s  += part2[(br*64+blk)*2+0];
      s2 += part2[(br*64+blk)*2+1];
    }
    double mean = s / MTOT;
    double var = s2 / MTOT - mean*mean;
    double r2 = 1.0 / sqrt(var + 1e-5);
    double sc = (double)eg2[br] * r2;
    consts2[br*2+0] = (float)sc;
    consts2[br*2+1] = (float)((double)ebt2[br] - sc*mean);
  }
}

// ---------------- pixel shuffle + sigmoid ----------------
__global__ __launch_bounds__(256) void out_k(const float* __restrict__ f,
    const float* __restrict__ maxo, const float* __restrict__ mino,
    const float* __restrict__ consts2, float* __restrict__ out) {
  int tid = blockIdx.x*256 + threadIdx.x;   // 65536
  int b = tid >> 14;
  int y = (tid >> 7) & 127, xx = tid & 127;
  int n = ((y>>1)<<6) + (xx>>1);
  int ch = ((y&1)<<1) + (xx&1);
  float v;
  if (ch == 0) {
    v = f[b*NPIX + n];
  } else {
    int br = ch - 1;
    float sc = consts2[br*2+0], sh = consts2[br*2+1];
    float base = (sc >= 0.f) ? maxo[br*NROWS + b*NPIX + n]
                             : mino[br*NROWS + b*NPIX + n];
    v = fmaxf(fmaf(sc, base, sh), 0.f);
  }
  out[tid] = 1.f / (1.f + expf(-v));
}

extern "C" void kernel_launch(void* const* d_in, const int* in_sizes, int n_in,
                              void* d_out, int out_size, void* d_ws, size_t ws_size,
                              hipStream_t stream) {
  (void)in_sizes; (void)n_in; (void)out_size; (void)ws_size;
  const float* x    = (const float*)d_in[0];
  const float* c1w  = (const float*)d_in[1];
  const float* c1b  = (const float*)d_in[2];
  const float* c2w  = (const float*)d_in[3];
  const float* c2b  = (const float*)d_in[4];
  const float* c3w  = (const float*)d_in[5];
  const float* c3b  = (const float*)d_in[6];
  const float* c4w  = (const float*)d_in[7];
  const float* c4b  = (const float*)d_in[8];
  const float* ew1  = (const float*)d_in[9];
  const float* eb1  = (const float*)d_in[10];
  const float* eg1  = (const float*)d_in[11];
  const float* ebt1 = (const float*)d_in[12];
  const float* ew2  = (const float*)d_in[13];
  const float* eb2  = (const float*)d_in[14];
  const float* eg2  = (const float*)d_in[15];
  const float* ebt2 = (const float*)d_in[16];
  float* out = (float*)d_out;

  float* c1      = (float*)d_ws;             // 1048576 floats
  float* c2      = c1 + 1048576;             // 524288
  float* c3      = c2 + 524288;              // 262144
  float* fbuf    = c3 + 262144;              // 16384
  float* dw      = fbuf + 16384;             // 327680
  double* part1  = (double*)(dw + 327680);   // 320
  float* consts1 = (float*)(part1 + 320);    // 144
  double* part2  = (double*)(consts1 + 144); // 384
  float* maxo    = (float*)(part2 + 384);    // 49152
  float* mino    = maxo + 49152;             // 49152
  float* consts2 = mino + 49152;             // 6 (+pad 2)
  float* svalw   = consts2 + 8;              // 16384
  int*   sidxw   = (int*)(svalw + 16384);    // 16384
  int*   rankw   = sidxw + 16384;            // 16384

  conv1_k<<<dim3(4,64), 256, 0, stream>>>(x, c1w, c1b, c1);
  conv3x3b_k<64,32,8,true ><<<dim3(4,64), 256, 0, stream>>>(c1, c2w, c2b, c2);
  conv3x3b_k<32,16,4,true ><<<dim3(4,64), 256, 0, stream>>>(c2, c3w, c3b, c3);
  conv4_k<<<dim3(4,16), 256, 0, stream>>>(c3, c4w, c4b, fbuf);
  sort_k<<<4, 1024, 0, stream>>>(fbuf, svalw, sidxw, rankw);
  knn2_k<<<64, 256, 0, stream>>>(fbuf, svalw, sidxw, rankw, dw, part1);
  finalize1_k<<<1, 64, 0, stream>>>(part1, ew1, eb1, eg1, ebt1, consts1);
  branch_k<<<dim3(64,3), 256, 0, stream>>>(fbuf, dw, consts1, ew2, eb2, maxo, mino, part2);
  finalize2_k<<<1, 64, 0, stream>>>(part2, eg2, ebt2, consts2);
  out_k<<<256, 256, 0, stream>>>(fbuf, maxo, mino, consts2, out);
}

// Round 5
// 157.916 us; speedup vs baseline: 16.5233x; 1.1761x over previous
//
#include <hip/hip_runtime.h>
#include <math.h>

#define NPIX 4096
#define NROWS 16384      // B*N
#define KN 20
#define MTOT 327680.0    // B*N*K

// ---------------- conv1: 5x5, 1->64, pad 2, tanh ----------------
__global__ __launch_bounds__(256) void conv1_k(const float* __restrict__ x,
    const float* __restrict__ w, const float* __restrict__ bias,
    float* __restrict__ out) {
  int b = blockIdx.x, co = blockIdx.y;
  __shared__ float tile[68*68];
  __shared__ float wt[25];
  const float* src = x + b*NPIX;
  for (int i = threadIdx.x; i < 68*68; i += 256) {
    int r = i/68 - 2, c = i%68 - 2;
    tile[i] = (r>=0 && r<64 && c>=0 && c<64) ? src[r*64+c] : 0.f;
  }
  if (threadIdx.x < 25) wt[threadIdx.x] = w[co*25 + threadIdx.x];
  __syncthreads();
  float bv = bias[co];
  for (int p = threadIdx.x; p < NPIX; p += 256) {
    int r = p >> 6, c = p & 63;
    float acc = bv;
#pragma unroll
    for (int di=0; di<5; di++)
#pragma unroll
      for (int dj=0; dj<5; dj++)
        acc = fmaf(tile[(r+di)*68 + c+dj], wt[di*5+dj], acc);
    out[(b*64+co)*NPIX + p] = tanhf(acc);
  }
}

// ---------------- 3x3 conv, all-cin single-stage, 8x8 tile ----------------
template<int CIN, int COUT, int OC, bool TANH>
__global__ __launch_bounds__(256) void conv3x3b_k(const float* __restrict__ in,
    const float* __restrict__ w, const float* __restrict__ bias,
    float* __restrict__ out) {
  int b = blockIdx.x, tile = blockIdx.y;
  int th = (tile >> 3) << 3, tw = (tile & 7) << 3;
  __shared__ float s_in[CIN*120];           // CIN x 10 x stride12
  for (int i = threadIdx.x; i < CIN*100; i += 256) {
    int cin = i / 100, rem = i - cin*100;
    int r = rem / 10, c = rem - r*10;
    int gr = th + r - 1, gc = tw + c - 1;
    float v = 0.f;
    if (gr >= 0 && gr < 64 && gc >= 0 && gc < 64)
      v = in[(((size_t)b*CIN + cin) << 12) + (gr << 6) + gc];
    s_in[cin*120 + r*12 + c] = v;
  }
  __syncthreads();
  int pix = threadIdx.x & 63;
  int py = pix >> 3, px = pix & 7;
  int og = __builtin_amdgcn_readfirstlane(threadIdx.x >> 6);  // wave-uniform
  const float* wb = w + og*OC*CIN*9;
  const float* bb = bias + og*OC;
  float acc[OC];
#pragma unroll
  for (int o=0;o<OC;o++) acc[o] = bb[o];
  for (int cin = 0; cin < CIN; cin++) {
    float v[9];
#pragma unroll
    for (int di=0;di<3;di++)
#pragma unroll
      for (int dj=0;dj<3;dj++)
        v[di*3+dj] = s_in[cin*120 + (py+di)*12 + px+dj];
    const float* wc = wb + cin*9;
#pragma unroll
    for (int o=0;o<OC;o++)
#pragma unroll
      for (int t=0;t<9;t++)
        acc[o] = fmaf(v[t], wc[o*CIN*9 + t], acc[o]);
  }
#pragma unroll
  for (int o=0;o<OC;o++) {
    float r = TANH ? tanhf(acc[o]) : acc[o];
    out[(((size_t)b*COUT + og*OC + o) << 12) + ((th+py)<<6) + (tw+px)] = r;
  }
}

// ---------------- conv4: 3x3, 16->1, no activation, 16x16 tile ----------------
__global__ __launch_bounds__(256) void conv4_k(const float* __restrict__ in,
    const float* __restrict__ w, const float* __restrict__ bias,
    float* __restrict__ out) {
  int b = blockIdx.x, tile = blockIdx.y;
  int th = (tile >> 2) << 4, tw = (tile & 3) << 4;
  __shared__ float s_in[16*18*20];          // 16 x 18 x stride20
  for (int i = threadIdx.x; i < 16*324; i += 256) {
    int cin = i / 324, rem = i - cin*324;
    int r = rem / 18, c = rem - r*18;
    int gr = th + r - 1, gc = tw + c - 1;
    float v = 0.f;
    if (gr >= 0 && gr < 64 && gc >= 0 && gc < 64)
      v = in[(((size_t)b*16 + cin) << 12) + (gr << 6) + gc];
    s_in[cin*360 + r*20 + c] = v;
  }
  __syncthreads();
  int ty = threadIdx.x >> 4, tx = threadIdx.x & 15;
  float acc = bias[0];
  for (int cin = 0; cin < 16; cin++) {
#pragma unroll
    for (int di=0;di<3;di++)
#pragma unroll
      for (int dj=0;dj<3;dj++)
        acc = fmaf(s_in[cin*360 + (ty+di)*20 + tx+dj], w[cin*9 + di*3+dj], acc);
  }
  out[((size_t)b << 12) + ((th+ty)<<6) + (tw+tx)] = acc;
}

// ---------------- register-blocked bitonic sort (per batch) ----------------
__device__ inline unsigned long long shflx64(unsigned long long v, int m) {
  unsigned lo = (unsigned)v, hi = (unsigned)(v >> 32);
  lo = __shfl_xor(lo, m, 64);
  hi = __shfl_xor(hi, m, 64);
  return (((unsigned long long)hi) << 32) | lo;
}

__global__ __launch_bounds__(1024) void sort_k(const float* __restrict__ f,
    float* __restrict__ sval, int* __restrict__ sidx) {
  int b = blockIdx.x;
  int l = threadIdx.x & 63;
  int w = threadIdx.x >> 6;
  __shared__ unsigned long long lds0[NPIX];
  __shared__ unsigned long long lds1[NPIX];
  const float* fb = f + b*NPIX;
  unsigned long long key[4];
#pragma unroll
  for (int r=0;r<4;r++) {
    unsigned e = (w<<8) + (r<<6) + l;
    float v = fb[e];
    unsigned u = __float_as_uint(v);
    u ^= (u >> 31) ? 0xFFFFFFFFu : 0x80000000u;   // order-preserving flip
    key[r] = (((unsigned long long)u) << 32) | e;
  }
  int bufsel = 0;
  for (unsigned k = 2; k <= 4096; k <<= 1) {
    for (unsigned j = k >> 1; j > 0; j >>= 1) {
      if (j >= 256) {
        unsigned long long* buf = bufsel ? lds1 : lds0;
        bufsel ^= 1;
#pragma unroll
        for (int r=0;r<4;r++) buf[(w<<8)+(r<<6)+l] = key[r];
        __syncthreads();
#pragma unroll
        for (int r=0;r<4;r++) {
          unsigned e = (w<<8)+(r<<6)+l;
          unsigned long long a = key[r];
          unsigned long long p = buf[e ^ j];
          bool up = ((e & k) == 0);
          bool keepmin = ((e & j) == 0) == up;
          bool sw = keepmin ? (p < a) : (p > a);
          key[r] = sw ? p : a;
        }
      } else if (j >= 64) {
        unsigned rj = j >> 6;
#pragma unroll
        for (int r=0;r<4;r++) {
          int pr = r ^ (int)rj;
          if (pr > r) {
            unsigned e = (w<<8)+((unsigned)r<<6)+l;
            bool up = ((e & k) == 0);
            unsigned long long a = key[r], c = key[pr];
            bool sw = up ? (c < a) : (c > a);
            if (sw) { key[r] = c; key[pr] = a; }
          }
        }
      } else {
#pragma unroll
        for (int r=0;r<4;r++) {
          unsigned e = (w<<8)+((unsigned)r<<6)+l;
          unsigned long long a = key[r];
          unsigned long long p = shflx64(a, (int)j);
          bool up = ((e & k) == 0);
          bool keepmin = ((e & j) == 0) == up;
          bool sw = keepmin ? (p < a) : (p > a);
          key[r] = sw ? p : a;
        }
      }
    }
  }
#pragma unroll
  for (int r=0;r<4;r++) {
    unsigned e = (w<<8)+((unsigned)r<<6)+l;    // sorted position
    unsigned u = (unsigned)(key[r] >> 32);
    u ^= (u >> 31) ? 0x80000000u : 0xFFFFFFFFu; // un-flip (inverse of flip)
    sval[b*NPIX + e] = __uint_as_float(u);
    sidx[b*NPIX + e] = (int)(key[r] & 0xFFFFFFFFu);
  }
}

// ---------------- KNN: one wave per point, cross-lane bitonic top-21 ----------------
// Lane l computes the exact reference-sequence dist key for window candidate
// start+l; a 64-key cross-lane bitonic sort (u64 keys, all distinct) yields
// stable-argsort order; lanes 1..20 write d = f[m]-f[n]. BN1 joint moments
// fused (f64, deterministic order).
__global__ __launch_bounds__(256) void knn3_k(const float* __restrict__ f,
    const float* __restrict__ sval, const int* __restrict__ sidx,
    float* __restrict__ dout, double* __restrict__ part) {
  int gw = (blockIdx.x << 2) + (threadIdx.x >> 6);  // global wave id
  int b = gw >> 12;          // 4096 waves per batch
  int s = gw & 4095;         // sorted position
  int l = threadIdx.x & 63;
  const float* svb = sval + b*NPIX;
  const int*   sib = sidx + b*NPIX;
  float fn = svb[s];
  int   n  = sib[s];
  int start = s - 32;
  if (start < 0) start = 0;
  if (start > NPIX - 64) start = NPIX - 64;
  int q = start + l;
  float fm = svb[q];
  int   m  = sib[q];
  float sqn = __fmul_rn(fn, fn);
  float pr  = __fmul_rn(fn, fm);
  float dist = __fsub_rn(__fadd_rn(sqn, __fmul_rn(fm, fm)), __fmul_rn(2.0f, pr));
  unsigned u = __float_as_uint(dist);
  u ^= (u >> 31) ? 0xFFFFFFFFu : 0x80000000u;
  unsigned long long key = (((unsigned long long)u) << 32) | (unsigned)m;
  // ascending bitonic sort of 64 keys across lanes
#pragma unroll
  for (int k = 2; k <= 64; k <<= 1) {
#pragma unroll
    for (int j = k >> 1; j > 0; j >>= 1) {
      unsigned long long p = shflx64(key, j);
      bool up = ((l & k) == 0);
      bool keepmin = ((l & j) == 0) == up;
      key = (keepmin ? (p < key) : (p > key)) ? p : key;
    }
  }
  int mr = (int)(key & 0xFFFFFFFFu);
  float d = __fsub_rn(f[b*NPIX + mr], fn);     // knn - x1 (rank l)
  if (l >= 1 && l <= 20)
    dout[(size_t)(b*NPIX + n)*KN + (l-1)] = d;
  // fused BN1 moments
  float dm = (l >= 1 && l <= 20) ? d : 0.f;
  double v0 = (double)dm, v1 = (double)dm * (double)dm;
#pragma unroll
  for (int off=32; off>0; off>>=1) {
    v0 += __shfl_down(v0, off, 64);
    v1 += __shfl_down(v1, off, 64);
  }
  __shared__ double sred[4][5];
  int wid = threadIdx.x >> 6;
  if (l == 0) {
    sred[wid][0] = (double)fn;
    sred[wid][1] = (double)fn * (double)fn;
    sred[wid][2] = v0;
    sred[wid][3] = v1;
    sred[wid][4] = (double)fn * v0;
  }
  __syncthreads();
  if (threadIdx.x == 0) {
#pragma unroll
    for (int qi=0; qi<5; qi++)
      part[blockIdx.x*5 + qi] = sred[0][qi]+sred[1][qi]+sred[2][qi]+sred[3][qi];
  }
}

// ---------------- fold BN1 into per-channel affine consts ----------------
__global__ __launch_bounds__(256) void finalize1_k(const double* __restrict__ part,
    const float* __restrict__ ew1, const float* __restrict__ eb1,
    const float* __restrict__ eg1, const float* __restrict__ ebt1,
    float* __restrict__ consts1) {
  __shared__ double S[256][5];
  int t = threadIdx.x;
  double a[5] = {0,0,0,0,0};
  for (int blk = t; blk < 4096; blk += 256)
#pragma unroll
    for (int q=0;q<5;q++) a[q] += part[blk*5+q];
#pragma unroll
  for (int q=0;q<5;q++) S[t][q] = a[q];
  __syncthreads();
  for (int st = 128; st > 0; st >>= 1) {
    if (t < st)
#pragma unroll
      for (int q=0;q<5;q++) S[t][q] += S[t+st][q];
    __syncthreads();
  }
  if (t == 0) {
    double Ef = S[0][0]/16384.0, Eff = S[0][1]/16384.0;
    double Ed = S[0][2]/MTOT, Edd = S[0][3]/MTOT, Efd = S[0][4]/MTOT;
    double Vf = Eff - Ef*Ef, Vd = Edd - Ed*Ed, Cfd = Efd - Ef*Ed;
    for (int br=0; br<3; br++)
      for (int c=0; c<16; c++) {
        int idx = br*16 + c;
        double w0 = (double)ew1[idx*2+0], w1 = (double)ew1[idx*2+1];
        double b1 = (double)eb1[idx];
        double m1 = w0*Ef + w1*Ed + b1;
        double v1 = w0*w0*Vf + 2.0*w0*w1*Cfd + w1*w1*Vd;
        double r1 = 1.0 / sqrt(v1 + 1e-5);
        double g = (double)eg1[idx];
        consts1[idx*3+0] = (float)(g*r1*w0);
        consts1[idx*3+1] = (float)(g*r1*w1);
        consts1[idx*3+2] = (float)(g*r1*(b1 - m1) + (double)ebt1[idx]);
      }
  }
}

// ---------------- per-branch o_pre: max/min over k + BN2 moments ----------------
__global__ __launch_bounds__(256) void branch_k(const float* __restrict__ f,
    const float* __restrict__ dw, const float* __restrict__ consts1,
    const float* __restrict__ ew2, const float* __restrict__ eb2,
    float* __restrict__ maxo, float* __restrict__ mino,
    double* __restrict__ part2) {
  int br = blockIdx.y;
  __shared__ float sA[16], sB[16], sC[16], sW[16];
  if (threadIdx.x < 16) {
    int idx = br*16 + threadIdx.x;
    sA[threadIdx.x] = consts1[idx*3+0];
    sB[threadIdx.x] = consts1[idx*3+1];
    sC[threadIdx.x] = consts1[idx*3+2];
    sW[threadIdx.x] = ew2[idx];
  }
  __syncthreads();
  int row = blockIdx.x*256 + threadIdx.x;
  float fv = f[row];
  const float* dd = dw + (size_t)row*KN;
  float b2 = eb2[br];
  float P[16];
#pragma unroll
  for (int c=0;c<16;c++) P[c] = fmaf(sA[c], fv, sC[c]);
  float mx = -INFINITY, mn = INFINITY;
  double s = 0.0, s2 = 0.0;
  for (int k=0;k<KN;k++) {
    float d = dd[k];
    float t = b2;
#pragma unroll
    for (int c=0;c<16;c++)
      t = fmaf(sW[c], fmaxf(fmaf(sB[c], d, P[c]), 0.f), t);
    mx = fmaxf(mx, t);
    mn = fminf(mn, t);
    double td = (double)t;
    s += td; s2 += td*td;
  }
  maxo[br*NROWS + row] = mx;
  mino[br*NROWS + row] = mn;
  __shared__ double sred[4][2];
  int wid = threadIdx.x >> 6, lane = threadIdx.x & 63;
  double v0 = s, v1 = s2;
  for (int off=32; off>0; off>>=1) {
    v0 += __shfl_down(v0, off, 64);
    v1 += __shfl_down(v1, off, 64);
  }
  if (lane == 0) { sred[wid][0] = v0; sred[wid][1] = v1; }
  __syncthreads();
  if (threadIdx.x == 0) {
    part2[(br*64 + blockIdx.x)*2 + 0] = sred[0][0]+sred[1][0]+sred[2][0]+sred[3][0];
    part2[(br*64 + blockIdx.x)*2 + 1] = sred[0][1]+sred[1][1]+sred[2][1]+sred[3][1];
  }
}

// ---------------- BN2 constants per branch ----------------
__global__ void finalize2_k(const double* __restrict__ part2,
    const float* __restrict__ eg2, const float* __restrict__ ebt2,
    float* __restrict__ consts2) {
  if (threadIdx.x || blockIdx.x) return;
  for (int br=0; br<3; br++) {
    double s=0, s2=0;
    for (int blk=0; blk<64; blk++) {
      s  += part2[(br*64+blk)*2+0];
      s2 += part2[(br*64+blk)*2+1];
    }
    double mean = s / MTOT;
    double var = s2 / MTOT - mean*mean;
    double r2 = 1.0 / sqrt(var + 1e-5);
    double sc = (double)eg2[br] * r2;
    consts2[br*2+0] = (float)sc;
    consts2[br*2+1] = (float)((double)ebt2[br] - sc*mean);
  }
}

// ---------------- pixel shuffle + sigmoid ----------------
__global__ __launch_bounds__(256) void out_k(const float* __restrict__ f,
    const float* __restrict__ maxo, const float* __restrict__ mino,
    const float* __restrict__ consts2, float* __restrict__ out) {
  int tid = blockIdx.x*256 + threadIdx.x;   // 65536
  int b = tid >> 14;
  int y = (tid >> 7) & 127, xx = tid & 127;
  int n = ((y>>1)<<6) + (xx>>1);
  int ch = ((y&1)<<1) + (xx&1);
  float v;
  if (ch == 0) {
    v = f[b*NPIX + n];
  } else {
    int br = ch - 1;
    float sc = consts2[br*2+0], sh = consts2[br*2+1];
    float base = (sc >= 0.f) ? maxo[br*NROWS + b*NPIX + n]
                             : mino[br*NROWS + b*NPIX + n];
    v = fmaxf(fmaf(sc, base, sh), 0.f);
  }
  out[tid] = 1.f / (1.f + expf(-v));
}

extern "C" void kernel_launch(void* const* d_in, const int* in_sizes, int n_in,
                              void* d_out, int out_size, void* d_ws, size_t ws_size,
                              hipStream_t stream) {
  (void)in_sizes; (void)n_in; (void)out_size; (void)ws_size;
  const float* x    = (const float*)d_in[0];
  const float* c1w  = (const float*)d_in[1];
  const float* c1b  = (const float*)d_in[2];
  const float* c2w  = (const float*)d_in[3];
  const float* c2b  = (const float*)d_in[4];
  const float* c3w  = (const float*)d_in[5];
  const float* c3b  = (const float*)d_in[6];
  const float* c4w  = (const float*)d_in[7];
  const float* c4b  = (const float*)d_in[8];
  const float* ew1  = (const float*)d_in[9];
  const float* eb1  = (const float*)d_in[10];
  const float* eg1  = (const float*)d_in[11];
  const float* ebt1 = (const float*)d_in[12];
  const float* ew2  = (const float*)d_in[13];
  const float* eb2  = (const float*)d_in[14];
  const float* eg2  = (const float*)d_in[15];
  const float* ebt2 = (const float*)d_in[16];
  float* out = (float*)d_out;

  float* c1      = (float*)d_ws;              // 1048576 floats
  float* c2      = c1 + 1048576;              // 524288
  float* c3      = c2 + 524288;               // 262144
  float* fbuf    = c3 + 262144;               // 16384
  float* dw      = fbuf + 16384;              // 327680
  double* part1  = (double*)(dw + 327680);    // 4096*5 doubles (8B aligned)
  float* consts1 = (float*)(part1 + 20480);   // 144
  double* part2  = (double*)(consts1 + 144);  // 384 doubles
  float* maxo    = (float*)(part2 + 384);     // 49152
  float* mino    = maxo + 49152;              // 49152
  float* consts2 = mino + 49152;              // 6 (+pad 2)
  float* svalw   = consts2 + 8;               // 16384
  int*   sidxw   = (int*)(svalw + 16384);     // 16384

  conv1_k<<<dim3(4,64), 256, 0, stream>>>(x, c1w, c1b, c1);
  conv3x3b_k<64,32,8,true ><<<dim3(4,64), 256, 0, stream>>>(c1, c2w, c2b, c2);
  conv3x3b_k<32,16,4,true ><<<dim3(4,64), 256, 0, stream>>>(c2, c3w, c3b, c3);
  conv4_k<<<dim3(4,16), 256, 0, stream>>>(c3, c4w, c4b, fbuf);
  sort_k<<<4, 1024, 0, stream>>>(fbuf, svalw, sidxw);
  knn3_k<<<4096, 256, 0, stream>>>(fbuf, svalw, sidxw, dw, part1);
  finalize1_k<<<1, 256, 0, stream>>>(part1, ew1, eb1, eg1, ebt1, consts1);
  branch_k<<<dim3(64,3), 256, 0, stream>>>(fbuf, dw, consts1, ew2, eb2, maxo, mino, part2);
  finalize2_k<<<1, 64, 0, stream>>>(part2, eg2, ebt2, consts2);
  out_k<<<256, 256, 0, stream>>>(fbuf, maxo, mino, consts2, out);
}

// Round 6
// 154.193 us; speedup vs baseline: 16.9222x; 1.0241x over previous
//
#include <hip/hip_runtime.h>
#include <math.h>

#define NPIX 4096
#define NROWS 16384      // B*N
#define KN 20
#define MTOT 327680.0    // B*N*K

// ---------------- conv1: 5x5, 1->64, pad 2, tanh; row-quarter blocks ----------------
__global__ __launch_bounds__(256) void conv1_k(const float* __restrict__ x,
    const float* __restrict__ w, const float* __restrict__ bias,
    float* __restrict__ out) {
  int bq = blockIdx.x;            // 16 = 4 batches x 4 quarters
  int b = bq >> 2, q = bq & 3;
  int co = blockIdx.y;
  __shared__ float tile[20*68];
  __shared__ float wt[25];
  const float* src = x + b*NPIX;
  int gr0 = (q << 4) - 2;
  for (int i = threadIdx.x; i < 20*68; i += 256) {
    int r = i/68, c = i%68;
    int gr = gr0 + r, gc = c - 2;
    tile[i] = (gr>=0 && gr<64 && gc>=0 && gc<64) ? src[(gr<<6)+gc] : 0.f;
  }
  if (threadIdx.x < 25) wt[threadIdx.x] = w[co*25 + threadIdx.x];
  __syncthreads();
  float bv = bias[co];
  for (int p = threadIdx.x; p < 1024; p += 256) {
    int pr = p >> 6, pc = p & 63;
    float acc = bv;
#pragma unroll
    for (int di=0; di<5; di++)
#pragma unroll
      for (int dj=0; dj<5; dj++)
        acc = fmaf(tile[(pr+di)*68 + pc+dj], wt[di*5+dj], acc);
    out[(b*64+co)*NPIX + ((q<<4)+pr)*64 + pc] = tanhf(acc);
  }
}

// ---------------- 3x3 conv, 1024 threads, 16 cout-groups x 64 px ----------------
// Per-output accumulation order: bias, then cin 0..CIN-1 with taps 0..8 —
// bit-identical to the verified round-5 kernel.
template<int CIN, int COUT, int OC, bool TANH>
__global__ __launch_bounds__(1024) void conv3x3c_k(const float* __restrict__ in,
    const float* __restrict__ w, const float* __restrict__ bias,
    float* __restrict__ out) {
  int b = blockIdx.x, tile = blockIdx.y;
  int th = (tile >> 3) << 3, tw = (tile & 7) << 3;
  __shared__ float s_in[CIN*120];           // CIN x 10 x stride12
  for (int i = threadIdx.x; i < CIN*100; i += 1024) {
    int cin = i / 100, rem = i - cin*100;
    int r = rem / 10, c = rem - r*10;
    int gr = th + r - 1, gc = tw + c - 1;
    float v = 0.f;
    if (gr >= 0 && gr < 64 && gc >= 0 && gc < 64)
      v = in[(((size_t)b*CIN + cin) << 12) + (gr << 6) + gc];
    s_in[cin*120 + r*12 + c] = v;
  }
  __syncthreads();
  int pix = threadIdx.x & 63;
  int py = pix >> 3, px = pix & 7;
  int og = __builtin_amdgcn_readfirstlane(threadIdx.x >> 6);  // wave-uniform 0..15
  const float* wb = w + og*OC*CIN*9;
  const float* bb = bias + og*OC;
  float acc[OC];
#pragma unroll
  for (int o=0;o<OC;o++) acc[o] = bb[o];
  for (int cin = 0; cin < CIN; cin++) {
    float v[9];
#pragma unroll
    for (int di=0;di<3;di++)
#pragma unroll
      for (int dj=0;dj<3;dj++)
        v[di*3+dj] = s_in[cin*120 + (py+di)*12 + px+dj];
    const float* wc = wb + cin*9;
#pragma unroll
    for (int o=0;o<OC;o++)
#pragma unroll
      for (int t=0;t<9;t++)
        acc[o] = fmaf(v[t], wc[o*CIN*9 + t], acc[o]);
  }
#pragma unroll
  for (int o=0;o<OC;o++) {
    float r = TANH ? tanhf(acc[o]) : acc[o];
    out[(((size_t)b*COUT + og*OC + o) << 12) + ((th+py)<<6) + (tw+px)] = r;
  }
}

// ---------------- conv4: 3x3, 16->1, 8x8 tiles, sequential cin ----------------
__global__ __launch_bounds__(256) void conv4_k(const float* __restrict__ in,
    const float* __restrict__ w, const float* __restrict__ bias,
    float* __restrict__ out) {
  int b = blockIdx.x, tile = blockIdx.y;
  int th = (tile >> 3) << 3, tw = (tile & 7) << 3;
  __shared__ float s_in[16*120];
  for (int i = threadIdx.x; i < 1600; i += 256) {
    int cin = i / 100, rem = i - cin*100;
    int r = rem / 10, c = rem - r*10;
    int gr = th + r - 1, gc = tw + c - 1;
    float v = 0.f;
    if (gr >= 0 && gr < 64 && gc >= 0 && gc < 64)
      v = in[(((size_t)b*16 + cin) << 12) + (gr << 6) + gc];
    s_in[cin*120 + r*12 + c] = v;
  }
  __syncthreads();
  if (threadIdx.x < 64) {
    int py = threadIdx.x >> 3, px = threadIdx.x & 7;
    float acc = bias[0];
    for (int cin = 0; cin < 16; cin++) {
#pragma unroll
      for (int di=0;di<3;di++)
#pragma unroll
        for (int dj=0;dj<3;dj++)
          acc = fmaf(s_in[cin*120 + (py+di)*12 + px+dj], w[cin*9 + di*3+dj], acc);
    }
    out[((size_t)b << 12) + ((th+py)<<6) + (tw+px)] = acc;
  }
}

// ---------------- sort: wave-local bitonic (256-runs) + merge-path merges ----------------
__device__ inline unsigned long long shflx64(unsigned long long v, int m) {
  unsigned lo = (unsigned)v, hi = (unsigned)(v >> 32);
  lo = __shfl_xor(lo, m, 64);
  hi = __shfl_xor(hi, m, 64);
  return (((unsigned long long)hi) << 32) | lo;
}

__global__ __launch_bounds__(1024) void sort2_k(const float* __restrict__ f,
    float* __restrict__ sval, int* __restrict__ sidx) {
  int b = blockIdx.x;
  int tid = threadIdx.x;
  int l = tid & 63, w = tid >> 6;
  __shared__ unsigned long long Ab[NPIX];
  __shared__ unsigned long long Bb[NPIX];
  const float* fb = f + b*NPIX;
  unsigned long long key[4];
#pragma unroll
  for (int r=0;r<4;r++) {
    unsigned e = (w<<8) + (r<<6) + l;
    float v = fb[e];
    unsigned u = __float_as_uint(v);
    u ^= (u >> 31) ? 0xFFFFFFFFu : 0x80000000u;   // order-preserving flip
    key[r] = (((unsigned long long)u) << 32) | e;
  }
  // phase A: sort each contiguous 256-run (one wave) ascending, barrier-free
  for (unsigned k = 2; k <= 256; k <<= 1) {
    for (unsigned j = k >> 1; j > 0; j >>= 1) {
      if (j >= 64) {
        unsigned rj = j >> 6;
#pragma unroll
        for (int r=0;r<4;r++) {
          int pr = r ^ (int)rj;
          if (pr > r) {
            unsigned e = (w<<8)+((unsigned)r<<6)+l;
            bool up = ((e & k & 255u) == 0);
            unsigned long long a = key[r], c = key[pr];
            bool sw = up ? (c < a) : (c > a);
            if (sw) { key[r] = c; key[pr] = a; }
          }
        }
      } else {
#pragma unroll
        for (int r=0;r<4;r++) {
          unsigned e = (w<<8)+((unsigned)r<<6)+l;
          unsigned long long a = key[r];
          unsigned long long p = shflx64(a, (int)j);
          bool up = ((e & k & 255u) == 0);
          bool keepmin = ((e & j) == 0) == up;
          key[r] = (keepmin ? (p < a) : (p > a)) ? p : a;
        }
      }
    }
  }
#pragma unroll
  for (int r=0;r<4;r++) Ab[(w<<8)+(r<<6)+l] = key[r];
  __syncthreads();
  // phase B: 4 merge rounds via per-element binary search (distinct keys -> stable)
  unsigned long long* src = Ab;
  unsigned long long* dst = Bb;
  for (int lg = 8; lg <= 11; lg++) {
    const int L = 1 << lg;
    int p0 = tid << 2;
    int ri = p0 >> lg;
    int base = (ri ^ 1) << lg;
    int mbase = ((ri >> 1) << (lg + 1)) + (p0 & (L - 1));
    unsigned long long kk[4];
    int lo[4], hi[4];
#pragma unroll
    for (int r=0;r<4;r++) { kk[r] = src[p0 + r]; lo[r] = 0; hi[r] = L; }
    for (int s = 0; s <= lg; s++) {
#pragma unroll
      for (int r=0;r<4;r++) {
        if (lo[r] < hi[r]) {
          int mid = (lo[r] + hi[r]) >> 1;
          if (src[base + mid] < kk[r]) lo[r] = mid + 1; else hi[r] = mid;
        }
      }
    }
#pragma unroll
    for (int r=0;r<4;r++) dst[mbase + r + lo[r]] = kk[r];
    __syncthreads();
    unsigned long long* t = src; src = dst; dst = t;
  }
#pragma unroll
  for (int r=0;r<4;r++) {
    int p = (tid << 2) + r;
    unsigned long long kk = src[p];
    unsigned u = (unsigned)(kk >> 32);
    u ^= (u >> 31) ? 0x80000000u : 0xFFFFFFFFu;   // un-flip
    sval[b*NPIX + p] = __uint_as_float(u);
    sidx[b*NPIX + p] = (int)(kk & 0xFFFFFFFFu);
  }
}

// ---------------- KNN: one wave per point, cross-lane bitonic top-21 ----------------
__global__ __launch_bounds__(256) void knn3_k(const float* __restrict__ f,
    const float* __restrict__ sval, const int* __restrict__ sidx,
    float* __restrict__ dout, double* __restrict__ part) {
  int gw = (blockIdx.x << 2) + (threadIdx.x >> 6);  // global wave id
  int b = gw >> 12;          // 4096 waves per batch
  int s = gw & 4095;         // sorted position
  int l = threadIdx.x & 63;
  const float* svb = sval + b*NPIX;
  const int*   sib = sidx + b*NPIX;
  float fn = svb[s];
  int   n  = sib[s];
  int start = s - 32;
  if (start < 0) start = 0;
  if (start > NPIX - 64) start = NPIX - 64;
  int q = start + l;
  float fm = svb[q];
  int   m  = sib[q];
  float sqn = __fmul_rn(fn, fn);
  float pr  = __fmul_rn(fn, fm);
  float dist = __fsub_rn(__fadd_rn(sqn, __fmul_rn(fm, fm)), __fmul_rn(2.0f, pr));
  unsigned u = __float_as_uint(dist);
  u ^= (u >> 31) ? 0xFFFFFFFFu : 0x80000000u;
  unsigned long long key = (((unsigned long long)u) << 32) | (unsigned)m;
#pragma unroll
  for (int k = 2; k <= 64; k <<= 1) {
#pragma unroll
    for (int j = k >> 1; j > 0; j >>= 1) {
      unsigned long long p = shflx64(key, j);
      bool up = ((l & k) == 0);
      bool keepmin = ((l & j) == 0) == up;
      key = (keepmin ? (p < key) : (p > key)) ? p : key;
    }
  }
  int mr = (int)(key & 0xFFFFFFFFu);
  float d = __fsub_rn(f[b*NPIX + mr], fn);     // knn - x1 (rank l)
  if (l >= 1 && l <= 20)
    dout[(size_t)(b*NPIX + n)*KN + (l-1)] = d;
  float dm = (l >= 1 && l <= 20) ? d : 0.f;
  double v0 = (double)dm, v1 = (double)dm * (double)dm;
#pragma unroll
  for (int off=32; off>0; off>>=1) {
    v0 += __shfl_down(v0, off, 64);
    v1 += __shfl_down(v1, off, 64);
  }
  __shared__ double sred[4][5];
  int wid = threadIdx.x >> 6;
  if (l == 0) {
    sred[wid][0] = (double)fn;
    sred[wid][1] = (double)fn * (double)fn;
    sred[wid][2] = v0;
    sred[wid][3] = v1;
    sred[wid][4] = (double)fn * v0;
  }
  __syncthreads();
  if (threadIdx.x == 0) {
#pragma unroll
    for (int qi=0; qi<5; qi++)
      part[blockIdx.x*5 + qi] = sred[0][qi]+sred[1][qi]+sred[2][qi]+sred[3][qi];
  }
}

// ---------------- fold BN1 into per-channel affine consts ----------------
__global__ __launch_bounds__(256) void finalize1_k(const double* __restrict__ part,
    const float* __restrict__ ew1, const float* __restrict__ eb1,
    const float* __restrict__ eg1, const float* __restrict__ ebt1,
    float* __restrict__ consts1) {
  __shared__ double S[256][5];
  int t = threadIdx.x;
  double a[5] = {0,0,0,0,0};
  for (int blk = t; blk < 4096; blk += 256)
#pragma unroll
    for (int q=0;q<5;q++) a[q] += part[blk*5+q];
#pragma unroll
  for (int q=0;q<5;q++) S[t][q] = a[q];
  __syncthreads();
  for (int st = 128; st > 0; st >>= 1) {
    if (t < st)
#pragma unroll
      for (int q=0;q<5;q++) S[t][q] += S[t+st][q];
    __syncthreads();
  }
  if (t == 0) {
    double Ef = S[0][0]/16384.0, Eff = S[0][1]/16384.0;
    double Ed = S[0][2]/MTOT, Edd = S[0][3]/MTOT, Efd = S[0][4]/MTOT;
    double Vf = Eff - Ef*Ef, Vd = Edd - Ed*Ed, Cfd = Efd - Ef*Ed;
    for (int br=0; br<3; br++)
      for (int c=0; c<16; c++) {
        int idx = br*16 + c;
        double w0 = (double)ew1[idx*2+0], w1 = (double)ew1[idx*2+1];
        double b1 = (double)eb1[idx];
        double m1 = w0*Ef + w1*Ed + b1;
        double v1 = w0*w0*Vf + 2.0*w0*w1*Cfd + w1*w1*Vd;
        double r1 = 1.0 / sqrt(v1 + 1e-5);
        double g = (double)eg1[idx];
        consts1[idx*3+0] = (float)(g*r1*w0);
        consts1[idx*3+1] = (float)(g*r1*w1);
        consts1[idx*3+2] = (float)(g*r1*(b1 - m1) + (double)ebt1[idx]);
      }
  }
}

// ---------------- per-branch o_pre: max/min over k + BN2 moments ----------------
__global__ __launch_bounds__(64) void branch_k(const float* __restrict__ f,
    const float* __restrict__ dw, const float* __restrict__ consts1,
    const float* __restrict__ ew2, const float* __restrict__ eb2,
    float* __restrict__ maxo, float* __restrict__ mino,
    double* __restrict__ part2) {
  int br = blockIdx.y;
  float sA[16], sB[16], sC[16], sW[16];
#pragma unroll
  for (int c=0;c<16;c++) {
    int idx = br*16 + c;
    sA[c] = consts1[idx*3+0];
    sB[c] = consts1[idx*3+1];
    sC[c] = consts1[idx*3+2];
    sW[c] = ew2[idx];
  }
  int row = blockIdx.x*64 + threadIdx.x;
  float fv = f[row];
  const float* dd = dw + (size_t)row*KN;
  float b2 = eb2[br];
  float P[16];
#pragma unroll
  for (int c=0;c<16;c++) P[c] = fmaf(sA[c], fv, sC[c]);
  float mx = -INFINITY, mn = INFINITY;
  double s = 0.0, s2 = 0.0;
  for (int k=0;k<KN;k++) {
    float d = dd[k];
    float t = b2;
#pragma unroll
    for (int c=0;c<16;c++)
      t = fmaf(sW[c], fmaxf(fmaf(sB[c], d, P[c]), 0.f), t);
    mx = fmaxf(mx, t);
    mn = fminf(mn, t);
    double td = (double)t;
    s += td; s2 += td*td;
  }
  maxo[br*NROWS + row] = mx;
  mino[br*NROWS + row] = mn;
  double v0 = s, v1 = s2;
#pragma unroll
  for (int off=32; off>0; off>>=1) {
    v0 += __shfl_down(v0, off, 64);
    v1 += __shfl_down(v1, off, 64);
  }
  if (threadIdx.x == 0) {
    part2[(br*256 + blockIdx.x)*2 + 0] = v0;
    part2[(br*256 + blockIdx.x)*2 + 1] = v1;
  }
}

// ---------------- BN2 constants per branch ----------------
__global__ void finalize2_k(const double* __restrict__ part2,
    const float* __restrict__ eg2, const float* __restrict__ ebt2,
    float* __restrict__ consts2) {
  if (threadIdx.x || blockIdx.x) return;
  for (int br=0; br<3; br++) {
    double s=0, s2=0;
    for (int blk=0; blk<256; blk++) {
      s  += part2[(br*256+blk)*2+0];
      s2 += part2[(br*256+blk)*2+1];
    }
    double mean = s / MTOT;
    double var = s2 / MTOT - mean*mean;
    double r2 = 1.0 / sqrt(var + 1e-5);
    double sc = (double)eg2[br] * r2;
    consts2[br*2+0] = (float)sc;
    consts2[br*2+1] = (float)((double)ebt2[br] - sc*mean);
  }
}

// ---------------- pixel shuffle + sigmoid ----------------
__global__ __launch_bounds__(256) void out_k(const float* __restrict__ f,
    const float* __restrict__ maxo, const float* __restrict__ mino,
    const float* __restrict__ consts2, float* __restrict__ out) {
  int tid = blockIdx.x*256 + threadIdx.x;   // 65536
  int b = tid >> 14;
  int y = (tid >> 7) & 127, xx = tid & 127;
  int n = ((y>>1)<<6) + (xx>>1);
  int ch = ((y&1)<<1) + (xx&1);
  float v;
  if (ch == 0) {
    v = f[b*NPIX + n];
  } else {
    int br = ch - 1;
    float sc = consts2[br*2+0], sh = consts2[br*2+1];
    float base = (sc >= 0.f) ? maxo[br*NROWS + b*NPIX + n]
                             : mino[br*NROWS + b*NPIX + n];
    v = fmaxf(fmaf(sc, base, sh), 0.f);
  }
  out[tid] = 1.f / (1.f + expf(-v));
}

extern "C" void kernel_launch(void* const* d_in, const int* in_sizes, int n_in,
                              void* d_out, int out_size, void* d_ws, size_t ws_size,
                              hipStream_t stream) {
  (void)in_sizes; (void)n_in; (void)out_size; (void)ws_size;
  const float* x    = (const float*)d_in[0];
  const float* c1w  = (const float*)d_in[1];
  const float* c1b  = (const float*)d_in[2];
  const float* c2w  = (const float*)d_in[3];
  const float* c2b  = (const float*)d_in[4];
  const float* c3w  = (const float*)d_in[5];
  const float* c3b  = (const float*)d_in[6];
  const float* c4w  = (const float*)d_in[7];
  const float* c4b  = (const float*)d_in[8];
  const float* ew1  = (const float*)d_in[9];
  const float* eb1  = (const float*)d_in[10];
  const float* eg1  = (const float*)d_in[11];
  const float* ebt1 = (const float*)d_in[12];
  const float* ew2  = (const float*)d_in[13];
  const float* eb2  = (const float*)d_in[14];
  const float* eg2  = (const float*)d_in[15];
  const float* ebt2 = (const float*)d_in[16];
  float* out = (float*)d_out;

  float* c1      = (float*)d_ws;              // 1048576 floats
  float* c2      = c1 + 1048576;              // 524288
  float* c3      = c2 + 524288;               // 262144
  float* fbuf    = c3 + 262144;               // 16384
  float* dw      = fbuf + 16384;              // 327680
  double* part1  = (double*)(dw + 327680);    // 4096*5 doubles
  float* consts1 = (float*)(part1 + 20480);   // 144
  double* part2  = (double*)(consts1 + 144);  // 1536 doubles
  float* maxo    = (float*)(part2 + 1536);    // 49152
  float* mino    = maxo + 49152;              // 49152
  float* consts2 = mino + 49152;              // 6 (+pad 2)
  float* svalw   = consts2 + 8;               // 16384
  int*   sidxw   = (int*)(svalw + 16384);     // 16384

  conv1_k<<<dim3(16,64), 256, 0, stream>>>(x, c1w, c1b, c1);
  conv3x3c_k<64,32,2,true ><<<dim3(4,64), 1024, 0, stream>>>(c1, c2w, c2b, c2);
  conv3x3c_k<32,16,1,true ><<<dim3(4,64), 1024, 0, stream>>>(c2, c3w, c3b, c3);
  conv4_k<<<dim3(4,64), 256, 0, stream>>>(c3, c4w, c4b, fbuf);
  sort2_k<<<4, 1024, 0, stream>>>(fbuf, svalw, sidxw);
  knn3_k<<<4096, 256, 0, stream>>>(fbuf, svalw, sidxw, dw, part1);
  finalize1_k<<<1, 256, 0, stream>>>(part1, ew1, eb1, eg1, ebt1, consts1);
  branch_k<<<dim3(256,3), 64, 0, stream>>>(fbuf, dw, consts1, ew2, eb2, maxo, mino, part2);
  finalize2_k<<<1, 64, 0, stream>>>(part2, eg2, ebt2, consts2);
  out_k<<<256, 256, 0, stream>>>(fbuf, maxo, mino, consts2, out);
}